// Round 9
// baseline (129.167 us; speedup 1.0000x reference)
//
#include <hip/hip_runtime.h>
#include <hip/hip_bf16.h>

typedef __attribute__((ext_vector_type(8))) short short8;   // 8 x bf16 (4 VGPRs)
typedef __attribute__((ext_vector_type(4))) float f32x4;
using bf16 = __hip_bfloat16;

// Problem sizes: B=32, LQ=LKV=256, HID=1024, EMB=1024, K_fc=2048

__device__ __forceinline__ void glds16(const void* g, void* lds) {
  __builtin_amdgcn_global_load_lds(
      (const __attribute__((address_space(1))) void*)g,
      (__attribute__((address_space(3))) void*)lds, 16, 0, 0);
}

// ---------------- K1: H->X convert, FW convert, ECT gather-transpose ----------------
// tasks 0..8191   : X[t][0:1024] = bf16(H[t])
// tasks 8192..9215: FW[t] = bf16(fc_w[t])
// tasks 9216..11263: gather+transpose Wc -> ECT[b][h][k]
__global__ __launch_bounds__(256) void k1_prep(
    const float* __restrict__ H, const float* __restrict__ fcw,
    const int* __restrict__ targets, const float* __restrict__ Wc,
    bf16* __restrict__ X, bf16* __restrict__ FW, bf16* __restrict__ ECT) {
  __shared__ float T[64][67];
  int task = blockIdx.x;
  int tid = threadIdx.x;
  if (task < 9216) {
    const float* src;
    bf16* dst;
    int n;
    if (task < 8192) {
      src = H + (size_t)task * 1024;
      dst = X + (size_t)task * 2048;
      n = 1024;
    } else {
      int t = task - 8192;
      src = fcw + (size_t)t * 2048;
      dst = FW + (size_t)t * 2048;
      n = 2048;
    }
    for (int c = tid * 4; c < n; c += 1024) {
      float4 v = *(const float4*)(src + c);
      __hip_bfloat162 p0, p1;
      p0.x = __float2bfloat16(v.x); p0.y = __float2bfloat16(v.y);
      p1.x = __float2bfloat16(v.z); p1.y = __float2bfloat16(v.w);
      *(__hip_bfloat162*)(dst + c) = p0;
      *(__hip_bfloat162*)(dst + c + 2) = p1;
    }
    return;
  }
  int bid = task - 9216;
  int b = bid >> 6;
  int kt = (bid >> 4) & 3;
  int ht = bid & 15;
#pragma unroll
  for (int p = 0; p < 4; ++p) {
    int k = p * 16 + (tid >> 4);
    int idx = targets[b * 256 + kt * 64 + k];
    const float* s = Wc + (size_t)idx * 1024 + ht * 64 + (tid & 15) * 4;
    float4 v = *(const float4*)s;
    int c = (tid & 15) * 4;
    T[k][c] = v.x; T[k][c + 1] = v.y; T[k][c + 2] = v.z; T[k][c + 3] = v.w;
  }
  __syncthreads();
#pragma unroll
  for (int p = 0; p < 8; ++p) {
    int h = p * 8 + (tid >> 5);
    int k = (tid & 31) * 2;
    __hip_bfloat162 o;
    o.x = __float2bfloat16(T[k][h]);
    o.y = __float2bfloat16(T[k + 1][h]);
    *(__hip_bfloat162*)(ECT + ((size_t)b * 1024 + ht * 64 + h) * 256 + kt * 64 + k) = o;
  }
}

// ---------------- K23: fused scores + masked-exp softmax + PV ----------------
// Scores B-operand gathered DIRECTLY from Wa (f32) via T14 reg-staging
// (issue loads before compute, cvt+ds_write after) — EA never materialized.
// Scores K-loop double-buffered; PV = flat 8-iter dbuf loop (np x kt), first
// ECT stage hoisted above softmax. Sync-only (no counted vmcnt anywhere).
__global__ __launch_bounds__(256, 1) void k23_scores_pv(
    bf16* __restrict__ X, const float* __restrict__ Wa,
    const int* __restrict__ captions, const bf16* __restrict__ ECT,
    const float* __restrict__ mask) {
  __shared__ __align__(16) char smem[16 * 1024 + 512 + 1024 + 128 * 1024];
  bf16* p_lds = (bf16*)smem;                          // 16KB [32][256] swizzled
  float* red  = (float*)(smem + 16 * 1024);           // 512B [4][32]
  int* idx_l  = (int*)(smem + 16 * 1024 + 512);       // 1KB captions[b]
  bf16* big   = (bf16*)(smem + 16 * 1024 + 512 + 1024); // 128KB

  int p = blockIdx.x;
  int wg = (p & 7) * 32 + (p >> 3);   // chunked XCD swizzle (256 % 8 == 0)
  int b = wg >> 3;
  int mb = wg & 7;
  int tid = threadIdx.x, w = tid >> 6, l = tid & 63;

  const bf16* Ag = X + ((size_t)b * 256 + mb * 32) * 2048;
  // scores double buffers inside big: per buf 18432 elems (A 2048 + B 16384)
  bf16* bufA[2] = {big, big + 18432};
  bf16* bufB[2] = {big + 2048, big + 18432 + 2048};

  f32x4 sacc[2][4];
  f32x4 zero = {0.f, 0.f, 0.f, 0.f};
#pragma unroll
  for (int m2 = 0; m2 < 2; ++m2)
#pragma unroll
    for (int n = 0; n < 4; ++n) sacc[m2][n] = zero;

  // ---- prologue: indices + tile 0 ----
  idx_l[tid] = captions[b * 256 + tid];
  {
    int row = tid >> 3, ssA = (tid & 7) ^ (row & 7);
    glds16(Ag + (size_t)row * 2048 + ssA * 8, bufA[0] + (size_t)w * 64 * 8);
  }
  __syncthreads();   // idx_l visible, A0 landed
  {
    float4 bv[8][2];
#pragma unroll
    for (int i = 0; i < 8; ++i) {
      int row = i * 32 + w * 8 + (l >> 3);
      int ss = (l & 7) ^ (row & 7);
      const float* src = Wa + (size_t)idx_l[row] * 1024 + ss * 8;
      bv[i][0] = *(const float4*)(src);
      bv[i][1] = *(const float4*)(src + 4);
    }
#pragma unroll
    for (int i = 0; i < 8; ++i) {
      union { short8 s; __hip_bfloat16 h[8]; } u;
      u.h[0] = __float2bfloat16(bv[i][0].x); u.h[1] = __float2bfloat16(bv[i][0].y);
      u.h[2] = __float2bfloat16(bv[i][0].z); u.h[3] = __float2bfloat16(bv[i][0].w);
      u.h[4] = __float2bfloat16(bv[i][1].x); u.h[5] = __float2bfloat16(bv[i][1].y);
      u.h[6] = __float2bfloat16(bv[i][1].z); u.h[7] = __float2bfloat16(bv[i][1].w);
      *(short8*)(bufB[0] + (size_t)(i * 256 + w * 64) * 8 + l * 8) = u.s;
    }
  }
  __syncthreads();   // B0 visible

  // ---- scores K-loop (16 tiles, double-buffered) ----
  for (int kt = 0; kt < 16; ++kt) {
    int cur = kt & 1;
    float4 bv[8][2];
    if (kt < 15) {
#pragma unroll
      for (int i = 0; i < 8; ++i) {          // issue B(kt+1) f32 loads early
        int row = i * 32 + w * 8 + (l >> 3);
        int ss = (l & 7) ^ (row & 7);
        const float* src = Wa + (size_t)idx_l[row] * 1024 + (kt + 1) * 64 + ss * 8;
        bv[i][0] = *(const float4*)(src);
        bv[i][1] = *(const float4*)(src + 4);
      }
      int row = tid >> 3, ssA = (tid & 7) ^ (row & 7);
      glds16(Ag + (size_t)row * 2048 + (kt + 1) * 64 + ssA * 8,
             bufA[cur ^ 1] + (size_t)w * 64 * 8);
    }
#pragma unroll
    for (int kk = 0; kk < 2; ++kk) {
      short8 a2[2];
#pragma unroll
      for (int m2 = 0; m2 < 2; ++m2) {
        int ar = m2 * 16 + (l & 15);
        int sl = kk * 4 + (l >> 4);
        a2[m2] = *(const short8*)(bufA[cur] + ar * 64 + ((sl ^ (ar & 7)) * 8));
      }
      __builtin_amdgcn_s_setprio(1);
#pragma unroll
      for (int n = 0; n < 4; ++n) {
        int rb = w * 64 + n * 16 + (l & 15);
        int sl = kk * 4 + (l >> 4);
        short8 bfr = *(const short8*)(bufB[cur] + rb * 64 + ((sl ^ (rb & 7)) * 8));
#pragma unroll
        for (int m2 = 0; m2 < 2; ++m2)
          sacc[m2][n] = __builtin_amdgcn_mfma_f32_16x16x32_bf16(
              a2[m2], bfr, sacc[m2][n], 0, 0, 0);
      }
      __builtin_amdgcn_s_setprio(0);
    }
    if (kt < 15) {                            // cvt + ds_write late (T14)
#pragma unroll
      for (int i = 0; i < 8; ++i) {
        union { short8 s; __hip_bfloat16 h[8]; } u;
        u.h[0] = __float2bfloat16(bv[i][0].x); u.h[1] = __float2bfloat16(bv[i][0].y);
        u.h[2] = __float2bfloat16(bv[i][0].z); u.h[3] = __float2bfloat16(bv[i][0].w);
        u.h[4] = __float2bfloat16(bv[i][1].x); u.h[5] = __float2bfloat16(bv[i][1].y);
        u.h[6] = __float2bfloat16(bv[i][1].z); u.h[7] = __float2bfloat16(bv[i][1].w);
        *(short8*)(bufB[cur ^ 1] + (size_t)(i * 256 + w * 64) * 8 + l * 8) = u.s;
      }
    }
    __syncthreads();
  }

  // ---- hoisted PV stage (np=0, kt=0) — overlaps softmax VALU ----
#pragma unroll
  for (int it = 0; it < 16; ++it) {
    int g = it * 64 + l;
    int row = g >> 3, ss = (g & 7) ^ (row & 7);
    glds16(ECT + ((size_t)b * 1024 + w * 128 + row) * 256 + ss * 8,
           big + (size_t)w * 8192 + (size_t)it * 512);
  }

  // ---- masked-exp softmax ----
  const float* mrow = mask + ((size_t)b * 256 + mb * 32) * 256;
  float s[2][4] = {{0.f, 0.f, 0.f, 0.f}, {0.f, 0.f, 0.f, 0.f}};
#pragma unroll
  for (int m2 = 0; m2 < 2; ++m2)
#pragma unroll
    for (int n = 0; n < 4; ++n)
#pragma unroll
      for (int i = 0; i < 4; ++i) {
        int r = m2 * 16 + ((l >> 4) << 2) + i;
        int c = w * 64 + n * 16 + (l & 15);
        float mv = mrow[r * 256 + c];
        mv = fminf(fmaxf(mv, 0.f), 1.f);
        float ev = expf(sacc[m2][n][i]) * mv;
        sacc[m2][n][i] = ev;
        s[m2][i] += ev;
      }
#pragma unroll
  for (int msk = 1; msk < 16; msk <<= 1)
#pragma unroll
    for (int m2 = 0; m2 < 2; ++m2)
#pragma unroll
      for (int i = 0; i < 4; ++i) s[m2][i] += __shfl_xor(s[m2][i], msk, 64);
  if ((l & 15) == 0) {
#pragma unroll
    for (int m2 = 0; m2 < 2; ++m2)
#pragma unroll
      for (int i = 0; i < 4; ++i)
        red[w * 32 + m2 * 16 + ((l >> 4) << 2) + i] = s[m2][i];
  }
  __syncthreads();
  float inv[2][4];
#pragma unroll
  for (int m2 = 0; m2 < 2; ++m2)
#pragma unroll
    for (int i = 0; i < 4; ++i) {
      int r = m2 * 16 + ((l >> 4) << 2) + i;
      float tot = red[r] + red[32 + r] + red[64 + r] + red[96 + r];
      inv[m2][i] = 1.f / (tot + 1e-10f);
    }
#pragma unroll
  for (int m2 = 0; m2 < 2; ++m2)
#pragma unroll
    for (int n = 0; n < 4; ++n)
#pragma unroll
      for (int i = 0; i < 4; ++i) {
        int r = m2 * 16 + ((l >> 4) << 2) + i;
        int c = w * 64 + n * 16 + (l & 15);
        float pv = sacc[m2][n][i] * inv[m2][i];
        p_lds[r * 256 + (((c >> 3) ^ (r & 7)) << 3) + (c & 7)] =
            __float2bfloat16(pv);
      }
  __syncthreads();   // p_lds visible + hoisted PV stage drained

  // ---- PV: flat 8-iter dbuf loop (idx = np*4 + kt) ----
  bf16* XO = X + ((size_t)b * 256 + mb * 32) * 2048 + 1024;
  f32x4 acc[2][8];
#pragma unroll
  for (int m2 = 0; m2 < 2; ++m2)
#pragma unroll
    for (int n = 0; n < 8; ++n) acc[m2][n] = zero;

  for (int idx = 0; idx < 8; ++idx) {
    int cur = idx & 1;
    int kt = idx & 3;
    if (idx < 7) {
      int jnp = (idx + 1) >> 2, jkt = (idx + 1) & 3;
#pragma unroll
      for (int it = 0; it < 16; ++it) {
        int g = it * 64 + l;
        int row = g >> 3, ss = (g & 7) ^ (row & 7);
        glds16(ECT + ((size_t)b * 1024 + jnp * 512 + w * 128 + row) * 256 +
                   jkt * 64 + ss * 8,
               big + (size_t)((cur ^ 1) * 4 + w) * 8192 + (size_t)it * 512);
      }
    }
    const bf16* Bw = big + (size_t)(cur * 4 + w) * 8192;
#pragma unroll
    for (int kk = 0; kk < 2; ++kk) {
      short8 a2[2];
#pragma unroll
      for (int m2 = 0; m2 < 2; ++m2) {
        int ar = m2 * 16 + (l & 15);
        int sl = kt * 8 + kk * 4 + (l >> 4);
        a2[m2] = *(const short8*)(p_lds + ar * 256 + ((sl ^ (ar & 7)) * 8));
      }
      __builtin_amdgcn_s_setprio(1);
#pragma unroll
      for (int n = 0; n < 8; ++n) {
        int rb = n * 16 + (l & 15);
        int sl = kk * 4 + (l >> 4);
        short8 bfr = *(const short8*)(Bw + rb * 64 + ((sl ^ (rb & 7)) * 8));
#pragma unroll
        for (int m2 = 0; m2 < 2; ++m2)
          acc[m2][n] = __builtin_amdgcn_mfma_f32_16x16x32_bf16(
              a2[m2], bfr, acc[m2][n], 0, 0, 0);
      }
      __builtin_amdgcn_s_setprio(0);
    }
    if (idx == 3 || idx == 7) {
      int np = idx >> 2;
#pragma unroll
      for (int m2 = 0; m2 < 2; ++m2)
#pragma unroll
        for (int n = 0; n < 8; ++n) {
          int rl = m2 * 16 + ((l >> 4) << 2);
          int col = np * 512 + w * 128 + n * 16 + (l & 15);
#pragma unroll
          for (int i = 0; i < 4; ++i)
            XO[(size_t)(rl + i) * 2048 + col] = __float2bfloat16(acc[m2][n][i]);
          acc[m2][n] = zero;
        }
    }
    __syncthreads();
  }
}

// ---------------- K4: out = X @ FW^T + fc_b + 1e-10 (f32) ----------------
// Proven sync-only 2-phase dbuf (R5-R8). At the m233 2-phase plateau.
#define K4A (256 * 64)
#define K4B (128 * 64)

__device__ __forceinline__ void k4_stage(const bf16* __restrict__ Ag,
                                         const bf16* __restrict__ Bg, int kt,
                                         bf16* As, bf16* Bs, int tid, int w) {
#pragma unroll
  for (int i = 0; i < 4; ++i) {
    int c = i * 512 + tid;
    int row = c >> 3, ss = (c & 7) ^ (row & 7);
    glds16(Ag + (size_t)row * 2048 + kt * 64 + ss * 8,
           As + (size_t)(i * 512 + w * 64) * 8);
  }
#pragma unroll
  for (int i = 0; i < 2; ++i) {
    int c = i * 512 + tid;
    int row = c >> 3, ss = (c & 7) ^ (row & 7);
    glds16(Bg + (size_t)row * 2048 + kt * 64 + ss * 8,
           Bs + (size_t)(i * 512 + w * 64) * 8);
  }
}

__device__ __forceinline__ void k4_tile(const bf16* As, const bf16* Bs,
                                        int wr, int wc, int l,
                                        f32x4 (&acc)[4][4]) {
  short8 a[2][4], b[2][4];
#pragma unroll
  for (int kk = 0; kk < 2; ++kk)
#pragma unroll
    for (int n = 0; n < 4; ++n) {
      int row = wc * 64 + n * 16 + (l & 15);
      int slot = kk * 4 + (l >> 4);
      b[kk][n] = *(const short8*)(Bs + row * 64 + ((slot ^ (row & 7)) * 8));
    }
#pragma unroll
  for (int kk = 0; kk < 2; ++kk)
#pragma unroll
    for (int m = 0; m < 4; ++m) {
      int row = wr * 64 + m * 16 + (l & 15);
      int slot = kk * 4 + (l >> 4);
      a[kk][m] = *(const short8*)(As + row * 64 + ((slot ^ (row & 7)) * 8));
    }
  __builtin_amdgcn_s_setprio(1);
#pragma unroll
  for (int kk = 0; kk < 2; ++kk)
#pragma unroll
    for (int m = 0; m < 4; ++m)
#pragma unroll
      for (int n = 0; n < 4; ++n)
        acc[m][n] = __builtin_amdgcn_mfma_f32_16x16x32_bf16(
            a[kk][m], b[kk][n], acc[m][n], 0, 0, 0);
  __builtin_amdgcn_s_setprio(0);
}

__global__ __launch_bounds__(512, 1) void k4_fc(
    const bf16* __restrict__ X, const bf16* __restrict__ FW,
    const float* __restrict__ fcb, float* __restrict__ out) {
  __shared__ __align__(16) bf16 As[2][K4A];   // 64 KB
  __shared__ __align__(16) bf16 Bs[2][K4B];   // 32 KB
  int p = blockIdx.x;
  int wg = (p & 7) * 32 + (p >> 3);   // chunked XCD swizzle (256 % 8 == 0)
  int mb = wg >> 3;
  int nb = wg & 7;
  int tid = threadIdx.x, w = tid >> 6, l = tid & 63;
  int wr = w >> 1, wc = w & 1;
  f32x4 acc[4][4];
  f32x4 zero = {0.f, 0.f, 0.f, 0.f};
#pragma unroll
  for (int m = 0; m < 4; ++m)
#pragma unroll
    for (int n = 0; n < 4; ++n) acc[m][n] = zero;

  const bf16* Ag = X + (size_t)mb * 256 * 2048;
  const bf16* Bg = FW + (size_t)nb * 128 * 2048;

  k4_stage(Ag, Bg, 0, As[0], Bs[0], tid, w);
  __syncthreads();
  for (int t = 0; t < 32; ++t) {
    int cur = t & 1;
    if (t < 31)
      k4_stage(Ag, Bg, t + 1, As[cur ^ 1], Bs[cur ^ 1], tid, w);
    k4_tile(As[cur], Bs[cur], wr, wc, l, acc);
    __syncthreads();
  }

  float bias[4];
#pragma unroll
  for (int n = 0; n < 4; ++n)
    bias[n] = fcb[nb * 128 + wc * 64 + n * 16 + (l & 15)];
#pragma unroll
  for (int m = 0; m < 4; ++m) {
    int rbase = mb * 256 + wr * 64 + m * 16 + ((l >> 4) << 2);
#pragma unroll
    for (int n = 0; n < 4; ++n) {
      int col = nb * 128 + wc * 64 + n * 16 + (l & 15);
#pragma unroll
      for (int i = 0; i < 4; ++i)
        out[(size_t)(rbase + i) * 1024 + col] = acc[m][n][i] + bias[n] + 1e-10f;
    }
  }
}

// ---------------- K5: in-place row L2 normalize ----------------
__global__ __launch_bounds__(256) void k5_norm(float* __restrict__ y) {
  __shared__ float red[4];
  int row = blockIdx.x;
  float* p = y + (size_t)row * 1024;
  int tid = threadIdx.x;
  float4 v = *(const float4*)(p + tid * 4);
  float ss = v.x * v.x + v.y * v.y + v.z * v.z + v.w * v.w;
#pragma unroll
  for (int m = 1; m < 64; m <<= 1) ss += __shfl_xor(ss, m, 64);
  if ((tid & 63) == 0) red[tid >> 6] = ss;
  __syncthreads();
  float tot = red[0] + red[1] + red[2] + red[3];
  float inv = 1.f / (sqrtf(tot) + 1e-8f);
  float4 o;
  o.x = v.x * inv; o.y = v.y * inv; o.z = v.z * inv; o.w = v.w * inv;
  *(float4*)(p + tid * 4) = o;
}

extern "C" void kernel_launch(void* const* d_in, const int* in_sizes, int n_in,
                              void* d_out, int out_size, void* d_ws, size_t ws_size,
                              hipStream_t stream) {
  const int* captions = (const int*)d_in[0];
  const float* H = (const float*)d_in[1];
  const int* targets = (const int*)d_in[2];
  const float* mask = (const float*)d_in[3];
  const float* Wa = (const float*)d_in[4];
  const float* Wc = (const float*)d_in[5];
  const float* fcw = (const float*)d_in[6];
  const float* fcb = (const float*)d_in[7];
  float* out = (float*)d_out;

  char* ws = (char*)d_ws;
  bf16* ECT = (bf16*)(ws + (16u << 20));         // 16 MB [32][1024][256]
  bf16* X = (bf16*)(ws + (36u << 20));           // 32 MB [8192][2048]
  bf16* FW = (bf16*)(ws + (68u << 20));          //  4 MB [1024][2048]

  k1_prep<<<11264, 256, 0, stream>>>(H, fcw, targets, Wc, X, FW, ECT);
  k23_scores_pv<<<256, 256, 0, stream>>>(X, Wa, captions, ECT, mask);
  k4_fc<<<256, 512, 0, stream>>>(X, FW, fcb, out);
  k5_norm<<<8192, 256, 0, stream>>>(out);
}

// Round 10
// 118.200 us; speedup vs baseline: 1.0928x; 1.0928x over previous
//
#include <hip/hip_runtime.h>
#include <hip/hip_bf16.h>

typedef __attribute__((ext_vector_type(8))) short short8;   // 8 x bf16 (4 VGPRs)
typedef __attribute__((ext_vector_type(4))) float f32x4;
using bf16 = __hip_bfloat16;

// Problem sizes: B=32, LQ=LKV=256, HID=1024, EMB=1024, K_fc=2048

__device__ __forceinline__ void glds16(const void* g, void* lds) {
  __builtin_amdgcn_global_load_lds(
      (const __attribute__((address_space(1))) void*)g,
      (__attribute__((address_space(3))) void*)lds, 16, 0, 0);
}

// ---------------- K1: gathers + f32->bf16 conversions (merged) ----------------
__global__ __launch_bounds__(256) void k1_prep(
    const int* __restrict__ captions, const float* __restrict__ Wa,
    const float* __restrict__ H, const float* __restrict__ fcw,
    const int* __restrict__ targets, const float* __restrict__ Wc,
    bf16* __restrict__ EA, bf16* __restrict__ X, bf16* __restrict__ FW,
    bf16* __restrict__ ECT) {
  __shared__ float T[64][67];
  int task = blockIdx.x;
  int tid = threadIdx.x;
  if (task < 17408) {
    const float* src;
    bf16* dst;
    int n;
    if (task < 8192) {
      src = Wa + (size_t)captions[task] * 1024;
      dst = EA + (size_t)task * 1024;
      n = 1024;
    } else if (task < 16384) {
      int t = task - 8192;
      src = H + (size_t)t * 1024;
      dst = X + (size_t)t * 2048;
      n = 1024;
    } else {
      int t = task - 16384;
      src = fcw + (size_t)t * 2048;
      dst = FW + (size_t)t * 2048;
      n = 2048;
    }
    for (int c = tid * 4; c < n; c += 1024) {
      float4 v = *(const float4*)(src + c);
      __hip_bfloat162 p0, p1;
      p0.x = __float2bfloat16(v.x); p0.y = __float2bfloat16(v.y);
      p1.x = __float2bfloat16(v.z); p1.y = __float2bfloat16(v.w);
      *(__hip_bfloat162*)(dst + c) = p0;
      *(__hip_bfloat162*)(dst + c + 2) = p1;
    }
    return;
  }
  int bid = task - 17408;
  int b = bid >> 6;
  int kt = (bid >> 4) & 3;
  int ht = bid & 15;
#pragma unroll
  for (int p = 0; p < 4; ++p) {
    int k = p * 16 + (tid >> 4);
    int idx = targets[b * 256 + kt * 64 + k];
    const float* s = Wc + (size_t)idx * 1024 + ht * 64 + (tid & 15) * 4;
    float4 v = *(const float4*)s;
    int c = (tid & 15) * 4;
    T[k][c] = v.x; T[k][c + 1] = v.y; T[k][c + 2] = v.z; T[k][c + 3] = v.w;
  }
  __syncthreads();
#pragma unroll
  for (int p = 0; p < 8; ++p) {
    int h = p * 8 + (tid >> 5);
    int k = (tid & 31) * 2;
    __hip_bfloat162 o;
    o.x = __float2bfloat16(T[k][h]);
    o.y = __float2bfloat16(T[k + 1][h]);
    *(__hip_bfloat162*)(ECT + ((size_t)b * 1024 + ht * 64 + h) * 256 + kt * 64 + k) = o;
  }
}

// ---------------- K23: fused scores + masked-exp softmax + PV ----------------
__global__ __launch_bounds__(256, 1) void k23_scores_pv(
    bf16* __restrict__ X, const bf16* __restrict__ EA,
    const bf16* __restrict__ ECT, const float* __restrict__ mask) {
  __shared__ __align__(16) char smem[16 * 1024 + 512 + 128 * 1024];
  bf16* p_lds = (bf16*)smem;                    // [32][256] swizzled
  float* red  = (float*)(smem + 16 * 1024);     // [4][32]
  bf16* big   = (bf16*)(smem + 16 * 1024 + 512);// 128KB: scores As+Bs / PV B2

  int p = blockIdx.x;
  int wg = (p & 7) * 32 + (p >> 3);   // chunked XCD swizzle (256 % 8 == 0)
  int b = wg >> 3;
  int mb = wg & 7;
  int tid = threadIdx.x, w = tid >> 6, l = tid & 63;

  const bf16* Ag = X + ((size_t)b * 256 + mb * 32) * 2048;
  const bf16* Bg = EA + (size_t)b * 256 * 1024;
  bf16* As = big;              // 32 x 64
  bf16* Bs = big + 32 * 64;    // 256 x 64

  f32x4 sacc[2][4];
  f32x4 zero = {0.f, 0.f, 0.f, 0.f};
#pragma unroll
  for (int m2 = 0; m2 < 2; ++m2)
#pragma unroll
    for (int n = 0; n < 4; ++n) sacc[m2][n] = zero;

  for (int kt = 0; kt < 16; ++kt) {
    {
      int row = tid >> 3, ss = (tid & 7) ^ (row & 7);
      glds16(Ag + (size_t)row * 2048 + kt * 64 + ss * 8,
             As + (size_t)w * 64 * 8);
    }
#pragma unroll
    for (int i = 0; i < 8; ++i) {
      int c = i * 256 + tid;
      int row = c >> 3, ss = (c & 7) ^ (row & 7);
      glds16(Bg + (size_t)row * 1024 + kt * 64 + ss * 8,
             Bs + (size_t)(i * 256 + w * 64) * 8);
    }
    __syncthreads();
#pragma unroll
    for (int kk = 0; kk < 2; ++kk) {
      short8 a2[2];
#pragma unroll
      for (int m2 = 0; m2 < 2; ++m2) {
        int ar = m2 * 16 + (l & 15);
        int sl = kk * 4 + (l >> 4);
        a2[m2] = *(const short8*)(As + ar * 64 + ((sl ^ (ar & 7)) * 8));
      }
      __builtin_amdgcn_s_setprio(1);
#pragma unroll
      for (int n = 0; n < 4; ++n) {
        int rb = w * 64 + n * 16 + (l & 15);
        int sl = kk * 4 + (l >> 4);
        short8 bfr = *(const short8*)(Bs + rb * 64 + ((sl ^ (rb & 7)) * 8));
#pragma unroll
        for (int m2 = 0; m2 < 2; ++m2)
          sacc[m2][n] = __builtin_amdgcn_mfma_f32_16x16x32_bf16(
              a2[m2], bfr, sacc[m2][n], 0, 0, 0);
      }
      __builtin_amdgcn_s_setprio(0);
    }
    __syncthreads();
  }

  const float* mrow = mask + ((size_t)b * 256 + mb * 32) * 256;
  float s[2][4] = {{0.f, 0.f, 0.f, 0.f}, {0.f, 0.f, 0.f, 0.f}};
#pragma unroll
  for (int m2 = 0; m2 < 2; ++m2)
#pragma unroll
    for (int n = 0; n < 4; ++n)
#pragma unroll
      for (int i = 0; i < 4; ++i) {
        int r = m2 * 16 + ((l >> 4) << 2) + i;
        int c = w * 64 + n * 16 + (l & 15);
        float mv = mrow[r * 256 + c];
        mv = fminf(fmaxf(mv, 0.f), 1.f);
        float ev = expf(sacc[m2][n][i]) * mv;
        sacc[m2][n][i] = ev;
        s[m2][i] += ev;
      }
#pragma unroll
  for (int msk = 1; msk < 16; msk <<= 1)
#pragma unroll
    for (int m2 = 0; m2 < 2; ++m2)
#pragma unroll
      for (int i = 0; i < 4; ++i) s[m2][i] += __shfl_xor(s[m2][i], msk, 64);
  if ((l & 15) == 0) {
#pragma unroll
    for (int m2 = 0; m2 < 2; ++m2)
#pragma unroll
      for (int i = 0; i < 4; ++i)
        red[w * 32 + m2 * 16 + ((l >> 4) << 2) + i] = s[m2][i];
  }
  __syncthreads();
  float inv[2][4];
#pragma unroll
  for (int m2 = 0; m2 < 2; ++m2)
#pragma unroll
    for (int i = 0; i < 4; ++i) {
      int r = m2 * 16 + ((l >> 4) << 2) + i;
      float tot = red[r] + red[32 + r] + red[64 + r] + red[96 + r];
      inv[m2][i] = 1.f / (tot + 1e-10f);
    }
#pragma unroll
  for (int m2 = 0; m2 < 2; ++m2)
#pragma unroll
    for (int n = 0; n < 4; ++n)
#pragma unroll
      for (int i = 0; i < 4; ++i) {
        int r = m2 * 16 + ((l >> 4) << 2) + i;
        int c = w * 64 + n * 16 + (l & 15);
        float pv = sacc[m2][n][i] * inv[m2][i];
        p_lds[r * 256 + (((c >> 3) ^ (r & 7)) << 3) + (c & 7)] =
            __float2bfloat16(pv);
      }
  __syncthreads();

  bf16* XO = X + ((size_t)b * 256 + mb * 32) * 2048 + 1024;
  for (int np = 0; np < 2; ++np) {
    f32x4 acc[2][8];
#pragma unroll
    for (int m2 = 0; m2 < 2; ++m2)
#pragma unroll
      for (int n = 0; n < 8; ++n) acc[m2][n] = zero;

#pragma unroll
    for (int it = 0; it < 16; ++it) {
      int g = it * 64 + l;
      int row = g >> 3, ss = (g & 7) ^ (row & 7);
      glds16(ECT + ((size_t)b * 1024 + np * 512 + w * 128 + row) * 256 + ss * 8,
             big + (size_t)(0 * 4 + w) * 8192 + (size_t)it * 512);
    }
    __syncthreads();
    for (int kt = 0; kt < 4; ++kt) {
      int cur = kt & 1;
      if (kt < 3) {
#pragma unroll
        for (int it = 0; it < 16; ++it) {
          int g = it * 64 + l;
          int row = g >> 3, ss = (g & 7) ^ (row & 7);
          glds16(ECT + ((size_t)b * 1024 + np * 512 + w * 128 + row) * 256 +
                     (kt + 1) * 64 + ss * 8,
                 big + (size_t)((cur ^ 1) * 4 + w) * 8192 + (size_t)it * 512);
        }
      }
      const bf16* Bw = big + (size_t)(cur * 4 + w) * 8192;
#pragma unroll
      for (int kk = 0; kk < 2; ++kk) {
        short8 a2[2];
#pragma unroll
        for (int m2 = 0; m2 < 2; ++m2) {
          int ar = m2 * 16 + (l & 15);
          int sl = kt * 8 + kk * 4 + (l >> 4);
          a2[m2] = *(const short8*)(p_lds + ar * 256 + ((sl ^ (ar & 7)) * 8));
        }
        __builtin_amdgcn_s_setprio(1);
#pragma unroll
        for (int n = 0; n < 8; ++n) {
          int rb = n * 16 + (l & 15);
          int sl = kk * 4 + (l >> 4);
          short8 bfr = *(const short8*)(Bw + rb * 64 + ((sl ^ (rb & 7)) * 8));
#pragma unroll
          for (int m2 = 0; m2 < 2; ++m2)
            acc[m2][n] = __builtin_amdgcn_mfma_f32_16x16x32_bf16(
                a2[m2], bfr, acc[m2][n], 0, 0, 0);
        }
        __builtin_amdgcn_s_setprio(0);
      }
      __syncthreads();
    }
#pragma unroll
    for (int m2 = 0; m2 < 2; ++m2)
#pragma unroll
      for (int n = 0; n < 8; ++n) {
        int rl = m2 * 16 + ((l >> 4) << 2);
        int col = np * 512 + w * 128 + n * 16 + (l & 15);
#pragma unroll
        for (int i = 0; i < 4; ++i)
          XO[(size_t)(rl + i) * 2048 + col] = __float2bfloat16(acc[m2][n][i]);
      }
  }
}

// ---------------- K4: out = X @ FW^T + fc_b + 1e-10 (f32) ----------------
// Proven sync-only 2-phase dbuf (R5/R6). At the m233 2-phase plateau.
#define K4A (256 * 64)
#define K4B (128 * 64)

__device__ __forceinline__ void k4_stage(const bf16* __restrict__ Ag,
                                         const bf16* __restrict__ Bg, int kt,
                                         bf16* As, bf16* Bs, int tid, int w) {
#pragma unroll
  for (int i = 0; i < 4; ++i) {
    int c = i * 512 + tid;
    int row = c >> 3, ss = (c & 7) ^ (row & 7);
    glds16(Ag + (size_t)row * 2048 + kt * 64 + ss * 8,
           As + (size_t)(i * 512 + w * 64) * 8);
  }
#pragma unroll
  for (int i = 0; i < 2; ++i) {
    int c = i * 512 + tid;
    int row = c >> 3, ss = (c & 7) ^ (row & 7);
    glds16(Bg + (size_t)row * 2048 + kt * 64 + ss * 8,
           Bs + (size_t)(i * 512 + w * 64) * 8);
  }
}

__device__ __forceinline__ void k4_tile(const bf16* As, const bf16* Bs,
                                        int wr, int wc, int l,
                                        f32x4 (&acc)[4][4]) {
  short8 a[2][4], b[2][4];
#pragma unroll
  for (int kk = 0; kk < 2; ++kk)
#pragma unroll
    for (int n = 0; n < 4; ++n) {
      int row = wc * 64 + n * 16 + (l & 15);
      int slot = kk * 4 + (l >> 4);
      b[kk][n] = *(const short8*)(Bs + row * 64 + ((slot ^ (row & 7)) * 8));
    }
#pragma unroll
  for (int kk = 0; kk < 2; ++kk)
#pragma unroll
    for (int m = 0; m < 4; ++m) {
      int row = wr * 64 + m * 16 + (l & 15);
      int slot = kk * 4 + (l >> 4);
      a[kk][m] = *(const short8*)(As + row * 64 + ((slot ^ (row & 7)) * 8));
    }
  __builtin_amdgcn_s_setprio(1);
#pragma unroll
  for (int kk = 0; kk < 2; ++kk)
#pragma unroll
    for (int m = 0; m < 4; ++m)
#pragma unroll
      for (int n = 0; n < 4; ++n)
        acc[m][n] = __builtin_amdgcn_mfma_f32_16x16x32_bf16(
            a[kk][m], b[kk][n], acc[m][n], 0, 0, 0);
  __builtin_amdgcn_s_setprio(0);
}

__global__ __launch_bounds__(512, 1) void k4_fc(
    const bf16* __restrict__ X, const bf16* __restrict__ FW,
    const float* __restrict__ fcb, float* __restrict__ out) {
  __shared__ __align__(16) bf16 As[2][K4A];   // 64 KB
  __shared__ __align__(16) bf16 Bs[2][K4B];   // 32 KB
  int p = blockIdx.x;
  int wg = (p & 7) * 32 + (p >> 3);   // chunked XCD swizzle (256 % 8 == 0)
  int mb = wg >> 3;
  int nb = wg & 7;
  int tid = threadIdx.x, w = tid >> 6, l = tid & 63;
  int wr = w >> 1, wc = w & 1;
  f32x4 acc[4][4];
  f32x4 zero = {0.f, 0.f, 0.f, 0.f};
#pragma unroll
  for (int m = 0; m < 4; ++m)
#pragma unroll
    for (int n = 0; n < 4; ++n) acc[m][n] = zero;

  const bf16* Ag = X + (size_t)mb * 256 * 2048;
  const bf16* Bg = FW + (size_t)nb * 128 * 2048;

  k4_stage(Ag, Bg, 0, As[0], Bs[0], tid, w);
  __syncthreads();
  for (int t = 0; t < 32; ++t) {
    int cur = t & 1;
    if (t < 31)
      k4_stage(Ag, Bg, t + 1, As[cur ^ 1], Bs[cur ^ 1], tid, w);
    k4_tile(As[cur], Bs[cur], wr, wc, l, acc);
    __syncthreads();
  }

  float bias[4];
#pragma unroll
  for (int n = 0; n < 4; ++n)
    bias[n] = fcb[nb * 128 + wc * 64 + n * 16 + (l & 15)];
#pragma unroll
  for (int m = 0; m < 4; ++m) {
    int rbase = mb * 256 + wr * 64 + m * 16 + ((l >> 4) << 2);
#pragma unroll
    for (int n = 0; n < 4; ++n) {
      int col = nb * 128 + wc * 64 + n * 16 + (l & 15);
#pragma unroll
      for (int i = 0; i < 4; ++i)
        out[(size_t)(rbase + i) * 1024 + col] = acc[m][n][i] + bias[n] + 1e-10f;
    }
  }
}

// ---------------- K5: in-place row L2 normalize ----------------
__global__ __launch_bounds__(256) void k5_norm(float* __restrict__ y) {
  __shared__ float red[4];
  int row = blockIdx.x;
  float* p = y + (size_t)row * 1024;
  int tid = threadIdx.x;
  float4 v = *(const float4*)(p + tid * 4);
  float ss = v.x * v.x + v.y * v.y + v.z * v.z + v.w * v.w;
#pragma unroll
  for (int m = 1; m < 64; m <<= 1) ss += __shfl_xor(ss, m, 64);
  if ((tid & 63) == 0) red[tid >> 6] = ss;
  __syncthreads();
  float tot = red[0] + red[1] + red[2] + red[3];
  float inv = 1.f / (sqrtf(tot) + 1e-8f);
  float4 o;
  o.x = v.x * inv; o.y = v.y * inv; o.z = v.z * inv; o.w = v.w * inv;
  *(float4*)(p + tid * 4) = o;
}

extern "C" void kernel_launch(void* const* d_in, const int* in_sizes, int n_in,
                              void* d_out, int out_size, void* d_ws, size_t ws_size,
                              hipStream_t stream) {
  const int* captions = (const int*)d_in[0];
  const float* H = (const float*)d_in[1];
  const int* targets = (const int*)d_in[2];
  const float* mask = (const float*)d_in[3];
  const float* Wa = (const float*)d_in[4];
  const float* Wc = (const float*)d_in[5];
  const float* fcw = (const float*)d_in[6];
  const float* fcb = (const float*)d_in[7];
  float* out = (float*)d_out;

  char* ws = (char*)d_ws;
  bf16* EA = (bf16*)(ws);                        // 16 MB [32][256][1024]
  bf16* ECT = (bf16*)(ws + (16u << 20));         // 16 MB [32][1024][256]
  bf16* X = (bf16*)(ws + (36u << 20));           // 32 MB [8192][2048]
  bf16* FW = (bf16*)(ws + (68u << 20));          //  4 MB [1024][2048]

  k1_prep<<<19456, 256, 0, stream>>>(captions, Wa, H, fcw, targets, Wc,
                                     EA, X, FW, ECT);
  k23_scores_pv<<<256, 256, 0, stream>>>(X, EA, ECT, mask);
  k4_fc<<<256, 512, 0, stream>>>(X, FW, fcb, out);
  k5_norm<<<8192, 256, 0, stream>>>(out);
}

// Round 11
// 109.671 us; speedup vs baseline: 1.1778x; 1.0778x over previous
//
#include <hip/hip_runtime.h>
#include <hip/hip_bf16.h>

typedef __attribute__((ext_vector_type(8))) short short8;   // 8 x bf16 (4 VGPRs)
typedef __attribute__((ext_vector_type(4))) float f32x4;
using bf16 = __hip_bfloat16;

// Problem sizes: B=32, LQ=LKV=256, HID=1024, EMB=1024, K_fc=2048

#define VMCNT(n) asm volatile("s_waitcnt vmcnt(" #n ")" ::: "memory")
#define LGK0     asm volatile("s_waitcnt lgkmcnt(0)" ::: "memory")
#define SBAR     __builtin_amdgcn_sched_barrier(0)

__device__ __forceinline__ void glds16(const void* g, void* lds) {
  __builtin_amdgcn_global_load_lds(
      (const __attribute__((address_space(1))) void*)g,
      (__attribute__((address_space(3))) void*)lds, 16, 0, 0);
}

__device__ __forceinline__ void barrier_raw() {
  asm volatile("" ::: "memory");
  __builtin_amdgcn_s_barrier();
  asm volatile("" ::: "memory");
}

// ---------------- K1: gathers + f32->bf16 conversions (merged) ----------------
__global__ __launch_bounds__(256) void k1_prep(
    const int* __restrict__ captions, const float* __restrict__ Wa,
    const float* __restrict__ H, const float* __restrict__ fcw,
    const int* __restrict__ targets, const float* __restrict__ Wc,
    bf16* __restrict__ EA, bf16* __restrict__ X, bf16* __restrict__ FW,
    bf16* __restrict__ ECT) {
  __shared__ float T[64][67];
  int task = blockIdx.x;
  int tid = threadIdx.x;
  if (task < 17408) {
    const float* src;
    bf16* dst;
    int n;
    if (task < 8192) {
      src = Wa + (size_t)captions[task] * 1024;
      dst = EA + (size_t)task * 1024;
      n = 1024;
    } else if (task < 16384) {
      int t = task - 8192;
      src = H + (size_t)t * 1024;
      dst = X + (size_t)t * 2048;
      n = 1024;
    } else {
      int t = task - 16384;
      src = fcw + (size_t)t * 2048;
      dst = FW + (size_t)t * 2048;
      n = 2048;
    }
    for (int c = tid * 4; c < n; c += 1024) {
      float4 v = *(const float4*)(src + c);
      __hip_bfloat162 p0, p1;
      p0.x = __float2bfloat16(v.x); p0.y = __float2bfloat16(v.y);
      p1.x = __float2bfloat16(v.z); p1.y = __float2bfloat16(v.w);
      *(__hip_bfloat162*)(dst + c) = p0;
      *(__hip_bfloat162*)(dst + c + 2) = p1;
    }
    return;
  }
  int bid = task - 17408;
  int b = bid >> 6;
  int kt = (bid >> 4) & 3;
  int ht = bid & 15;
#pragma unroll
  for (int p = 0; p < 4; ++p) {
    int k = p * 16 + (tid >> 4);
    int idx = targets[b * 256 + kt * 64 + k];
    const float* s = Wc + (size_t)idx * 1024 + ht * 64 + (tid & 15) * 4;
    float4 v = *(const float4*)s;
    int c = (tid & 15) * 4;
    T[k][c] = v.x; T[k][c + 1] = v.y; T[k][c + 2] = v.z; T[k][c + 3] = v.w;
  }
  __syncthreads();
#pragma unroll
  for (int p = 0; p < 8; ++p) {
    int h = p * 8 + (tid >> 5);
    int k = (tid & 31) * 2;
    __hip_bfloat162 o;
    o.x = __float2bfloat16(T[k][h]);
    o.y = __float2bfloat16(T[k + 1][h]);
    *(__hip_bfloat162*)(ECT + ((size_t)b * 1024 + ht * 64 + h) * 256 + kt * 64 + k) = o;
  }
}

// ---------------- K23: fused scores + masked-exp softmax + PV ----------------
__global__ __launch_bounds__(256, 1) void k23_scores_pv(
    bf16* __restrict__ X, const bf16* __restrict__ EA,
    const bf16* __restrict__ ECT, const float* __restrict__ mask) {
  __shared__ __align__(16) char smem[16 * 1024 + 512 + 128 * 1024];
  bf16* p_lds = (bf16*)smem;                    // [32][256] swizzled
  float* red  = (float*)(smem + 16 * 1024);     // [4][32]
  bf16* big   = (bf16*)(smem + 16 * 1024 + 512);// 128KB: scores As+Bs / PV B2

  int p = blockIdx.x;
  int wg = (p & 7) * 32 + (p >> 3);   // chunked XCD swizzle (256 % 8 == 0)
  int b = wg >> 3;
  int mb = wg & 7;
  int tid = threadIdx.x, w = tid >> 6, l = tid & 63;

  const bf16* Ag = X + ((size_t)b * 256 + mb * 32) * 2048;
  const bf16* Bg = EA + (size_t)b * 256 * 1024;
  bf16* As = big;              // 32 x 64
  bf16* Bs = big + 32 * 64;    // 256 x 64

  f32x4 sacc[2][4];
  f32x4 zero = {0.f, 0.f, 0.f, 0.f};
#pragma unroll
  for (int m2 = 0; m2 < 2; ++m2)
#pragma unroll
    for (int n = 0; n < 4; ++n) sacc[m2][n] = zero;

  for (int kt = 0; kt < 16; ++kt) {
    {
      int row = tid >> 3, ss = (tid & 7) ^ (row & 7);
      glds16(Ag + (size_t)row * 2048 + kt * 64 + ss * 8,
             As + (size_t)w * 64 * 8);
    }
#pragma unroll
    for (int i = 0; i < 8; ++i) {
      int c = i * 256 + tid;
      int row = c >> 3, ss = (c & 7) ^ (row & 7);
      glds16(Bg + (size_t)row * 1024 + kt * 64 + ss * 8,
             Bs + (size_t)(i * 256 + w * 64) * 8);
    }
    __syncthreads();
#pragma unroll
    for (int kk = 0; kk < 2; ++kk) {
      short8 a2[2];
#pragma unroll
      for (int m2 = 0; m2 < 2; ++m2) {
        int ar = m2 * 16 + (l & 15);
        int sl = kk * 4 + (l >> 4);
        a2[m2] = *(const short8*)(As + ar * 64 + ((sl ^ (ar & 7)) * 8));
      }
      __builtin_amdgcn_s_setprio(1);
#pragma unroll
      for (int n = 0; n < 4; ++n) {
        int rb = w * 64 + n * 16 + (l & 15);
        int sl = kk * 4 + (l >> 4);
        short8 bfr = *(const short8*)(Bs + rb * 64 + ((sl ^ (rb & 7)) * 8));
#pragma unroll
        for (int m2 = 0; m2 < 2; ++m2)
          sacc[m2][n] = __builtin_amdgcn_mfma_f32_16x16x32_bf16(
              a2[m2], bfr, sacc[m2][n], 0, 0, 0);
      }
      __builtin_amdgcn_s_setprio(0);
    }
    __syncthreads();
  }

  const float* mrow = mask + ((size_t)b * 256 + mb * 32) * 256;
  float s[2][4] = {{0.f, 0.f, 0.f, 0.f}, {0.f, 0.f, 0.f, 0.f}};
#pragma unroll
  for (int m2 = 0; m2 < 2; ++m2)
#pragma unroll
    for (int n = 0; n < 4; ++n)
#pragma unroll
      for (int i = 0; i < 4; ++i) {
        int r = m2 * 16 + ((l >> 4) << 2) + i;
        int c = w * 64 + n * 16 + (l & 15);
        float mv = mrow[r * 256 + c];
        mv = fminf(fmaxf(mv, 0.f), 1.f);
        float ev = expf(sacc[m2][n][i]) * mv;
        sacc[m2][n][i] = ev;
        s[m2][i] += ev;
      }
#pragma unroll
  for (int msk = 1; msk < 16; msk <<= 1)
#pragma unroll
    for (int m2 = 0; m2 < 2; ++m2)
#pragma unroll
      for (int i = 0; i < 4; ++i) s[m2][i] += __shfl_xor(s[m2][i], msk, 64);
  if ((l & 15) == 0) {
#pragma unroll
    for (int m2 = 0; m2 < 2; ++m2)
#pragma unroll
      for (int i = 0; i < 4; ++i)
        red[w * 32 + m2 * 16 + ((l >> 4) << 2) + i] = s[m2][i];
  }
  __syncthreads();
  float inv[2][4];
#pragma unroll
  for (int m2 = 0; m2 < 2; ++m2)
#pragma unroll
    for (int i = 0; i < 4; ++i) {
      int r = m2 * 16 + ((l >> 4) << 2) + i;
      float tot = red[r] + red[32 + r] + red[64 + r] + red[96 + r];
      inv[m2][i] = 1.f / (tot + 1e-10f);
    }
#pragma unroll
  for (int m2 = 0; m2 < 2; ++m2)
#pragma unroll
    for (int n = 0; n < 4; ++n)
#pragma unroll
      for (int i = 0; i < 4; ++i) {
        int r = m2 * 16 + ((l >> 4) << 2) + i;
        int c = w * 64 + n * 16 + (l & 15);
        float pv = sacc[m2][n][i] * inv[m2][i];
        p_lds[r * 256 + (((c >> 3) ^ (r & 7)) << 3) + (c & 7)] =
            __float2bfloat16(pv);
      }
  __syncthreads();

  bf16* XO = X + ((size_t)b * 256 + mb * 32) * 2048 + 1024;
  for (int np = 0; np < 2; ++np) {
    f32x4 acc[2][8];
#pragma unroll
    for (int m2 = 0; m2 < 2; ++m2)
#pragma unroll
      for (int n = 0; n < 8; ++n) acc[m2][n] = zero;

#pragma unroll
    for (int it = 0; it < 16; ++it) {
      int g = it * 64 + l;
      int row = g >> 3, ss = (g & 7) ^ (row & 7);
      glds16(ECT + ((size_t)b * 1024 + np * 512 + w * 128 + row) * 256 + ss * 8,
             big + (size_t)(0 * 4 + w) * 8192 + (size_t)it * 512);
    }
    __syncthreads();
    for (int kt = 0; kt < 4; ++kt) {
      int cur = kt & 1;
      if (kt < 3) {
#pragma unroll
        for (int it = 0; it < 16; ++it) {
          int g = it * 64 + l;
          int row = g >> 3, ss = (g & 7) ^ (row & 7);
          glds16(ECT + ((size_t)b * 1024 + np * 512 + w * 128 + row) * 256 +
                     (kt + 1) * 64 + ss * 8,
                 big + (size_t)((cur ^ 1) * 4 + w) * 8192 + (size_t)it * 512);
        }
      }
      const bf16* Bw = big + (size_t)(cur * 4 + w) * 8192;
#pragma unroll
      for (int kk = 0; kk < 2; ++kk) {
        short8 a2[2];
#pragma unroll
        for (int m2 = 0; m2 < 2; ++m2) {
          int ar = m2 * 16 + (l & 15);
          int sl = kt * 8 + kk * 4 + (l >> 4);
          a2[m2] = *(const short8*)(p_lds + ar * 256 + ((sl ^ (ar & 7)) * 8));
        }
        __builtin_amdgcn_s_setprio(1);
#pragma unroll
        for (int n = 0; n < 8; ++n) {
          int rb = n * 16 + (l & 15);
          int sl = kk * 4 + (l >> 4);
          short8 bfr = *(const short8*)(Bw + rb * 64 + ((sl ^ (rb & 7)) * 8));
#pragma unroll
          for (int m2 = 0; m2 < 2; ++m2)
            acc[m2][n] = __builtin_amdgcn_mfma_f32_16x16x32_bf16(
                a2[m2], bfr, acc[m2][n], 0, 0, 0);
        }
        __builtin_amdgcn_s_setprio(0);
      }
      __syncthreads();
    }
#pragma unroll
    for (int m2 = 0; m2 < 2; ++m2)
#pragma unroll
      for (int n = 0; n < 8; ++n) {
        int rl = m2 * 16 + ((l >> 4) << 2);
        int col = np * 512 + w * 128 + n * 16 + (l & 15);
#pragma unroll
        for (int i = 0; i < 4; ++i)
          XO[(size_t)(rl + i) * 2048 + col] = __float2bfloat16(acc[m2][n][i]);
      }
  }
}

// ---------------- K4: out = X @ FW^T + fc_b + 1e-10 (f32) ----------------
// Counted-vmcnt triple-buffer pipeline, attempt #3. Root-cause fix vs R2/R3:
// NO rotating LDS pointers (3-way PHI defeats addrspace inference -> flat_load
// -> flat increments vmcnt -> ledger corrupt -> reads of unwritten LDS). Here
// L[3][...] is a static __shared__ array and the loop is unrolled x3 so every
// buffer index is a compile-time literal -> guaranteed ds_read/ds-side only.
// Ledger: prologue 12 in flight; per body +6 -> vmcnt(12) retires exactly
// tile-t's 6 DMA loads; epilogue vmcnt(6)/vmcnt(0). Release = lgkmcnt(0) +
// sched_barrier(0) + s_barrier (rule #18). No other VMEM inside the loop.
#define K4E (256 * 64 + 128 * 64)   // elems per buffer: A 256x64 | B 128x64

__device__ __forceinline__ void k4_stage(const bf16* __restrict__ Ag,
                                         const bf16* __restrict__ Bg, int kt,
                                         bf16* Lb, int tid, int w) {
#pragma unroll
  for (int i = 0; i < 4; ++i) {            // A: 256 rows x 64 k = 32 KB
    int c = i * 512 + tid;
    int row = c >> 3, ss = (c & 7) ^ (row & 7);
    glds16(Ag + (size_t)row * 2048 + kt * 64 + ss * 8,
           Lb + (size_t)(i * 512 + w * 64) * 8);
  }
#pragma unroll
  for (int i = 0; i < 2; ++i) {            // B: 128 rows x 64 k = 16 KB
    int c = i * 512 + tid;
    int row = c >> 3, ss = (c & 7) ^ (row & 7);
    glds16(Bg + (size_t)row * 2048 + kt * 64 + ss * 8,
           Lb + (size_t)(256 * 64 + (i * 512 + w * 64) * 8));
  }
}

__device__ __forceinline__ void k4_tile(const bf16* Lb, int wr, int wc, int l,
                                        f32x4 (&acc)[4][4]) {
  const bf16* As = Lb;
  const bf16* Bs = Lb + 256 * 64;
  short8 a[2][4], b[2][4];
#pragma unroll
  for (int kk = 0; kk < 2; ++kk)
#pragma unroll
    for (int n = 0; n < 4; ++n) {
      int row = wc * 64 + n * 16 + (l & 15);
      int slot = kk * 4 + (l >> 4);
      b[kk][n] = *(const short8*)(Bs + row * 64 + ((slot ^ (row & 7)) * 8));
    }
#pragma unroll
  for (int kk = 0; kk < 2; ++kk)
#pragma unroll
    for (int m = 0; m < 4; ++m) {
      int row = wr * 64 + m * 16 + (l & 15);
      int slot = kk * 4 + (l >> 4);
      a[kk][m] = *(const short8*)(As + row * 64 + ((slot ^ (row & 7)) * 8));
    }
  __builtin_amdgcn_s_setprio(1);
#pragma unroll
  for (int kk = 0; kk < 2; ++kk)
#pragma unroll
    for (int m = 0; m < 4; ++m)
#pragma unroll
      for (int n = 0; n < 4; ++n)
        acc[m][n] = __builtin_amdgcn_mfma_f32_16x16x32_bf16(
            a[kk][m], b[kk][n], acc[m][n], 0, 0, 0);
  __builtin_amdgcn_s_setprio(0);
}

__global__ __launch_bounds__(512, 1) void k4_fc(
    const bf16* __restrict__ X, const bf16* __restrict__ FW,
    const float* __restrict__ fcb, float* __restrict__ out) {
  __shared__ __align__(16) bf16 L[3][K4E];   // 144 KB, static -> addrspace(3)
  int p = blockIdx.x;
  int wg = (p & 7) * 32 + (p >> 3);   // chunked XCD swizzle (256 % 8 == 0)
  int mb = wg >> 3;   // 0..31
  int nb = wg & 7;    // 0..7
  int tid = threadIdx.x, w = tid >> 6, l = tid & 63;
  int wr = w >> 1, wc = w & 1;
  f32x4 acc[4][4];
  f32x4 zero = {0.f, 0.f, 0.f, 0.f};
#pragma unroll
  for (int m = 0; m < 4; ++m)
#pragma unroll
    for (int n = 0; n < 4; ++n) acc[m][n] = zero;

  const bf16* Ag = X + (size_t)mb * 256 * 2048;
  const bf16* Bg = FW + (size_t)nb * 128 * 2048;

  // prologue: tiles 0,1 -> L[0],L[1]  (12 VMEM in flight)
  k4_stage(Ag, Bg, 0, L[0], tid, w);
  k4_stage(Ag, Bg, 1, L[1], tid, w);

  // tile t consumed from L[t%3]; tile t+2 staged into L[(t+2)%3]; t = 0..29
#define K4_BODY(T, C, S)                                   \
  k4_stage(Ag, Bg, (T) + 2, L[S], tid, w);                 \
  VMCNT(12); SBAR;                                         \
  barrier_raw(); SBAR;                                     \
  k4_tile(L[C], wr, wc, l, acc);                           \
  LGK0; SBAR;                                              \
  barrier_raw();

  for (int tt = 0; tt < 30; tt += 3) {
    K4_BODY(tt + 0, 0, 2)
    K4_BODY(tt + 1, 1, 0)
    K4_BODY(tt + 2, 2, 1)
  }
#undef K4_BODY
  // t = 30 (in L[0]; tile 31's 6 loads still in flight)
  VMCNT(6); SBAR;
  barrier_raw(); SBAR;
  k4_tile(L[0], wr, wc, l, acc);
  LGK0; SBAR;
  barrier_raw();
  // t = 31 (in L[1])
  VMCNT(0); SBAR;
  barrier_raw(); SBAR;
  k4_tile(L[1], wr, wc, l, acc);

  float bias[4];
#pragma unroll
  for (int n = 0; n < 4; ++n)
    bias[n] = fcb[nb * 128 + wc * 64 + n * 16 + (l & 15)];
#pragma unroll
  for (int m = 0; m < 4; ++m) {
    int rbase = mb * 256 + wr * 64 + m * 16 + ((l >> 4) << 2);
#pragma unroll
    for (int n = 0; n < 4; ++n) {
      int col = nb * 128 + wc * 64 + n * 16 + (l & 15);
#pragma unroll
      for (int i = 0; i < 4; ++i)
        out[(size_t)(rbase + i) * 1024 + col] = acc[m][n][i] + bias[n] + 1e-10f;
    }
  }
}

// ---------------- K5: in-place row L2 normalize ----------------
__global__ __launch_bounds__(256) void k5_norm(float* __restrict__ y) {
  __shared__ float red[4];
  int row = blockIdx.x;
  float* p = y + (size_t)row * 1024;
  int tid = threadIdx.x;
  float4 v = *(const float4*)(p + tid * 4);
  float ss = v.x * v.x + v.y * v.y + v.z * v.z + v.w * v.w;
#pragma unroll
  for (int m = 1; m < 64; m <<= 1) ss += __shfl_xor(ss, m, 64);
  if ((tid & 63) == 0) red[tid >> 6] = ss;
  __syncthreads();
  float tot = red[0] + red[1] + red[2] + red[3];
  float inv = 1.f / (sqrtf(tot) + 1e-8f);
  float4 o;
  o.x = v.x * inv; o.y = v.y * inv; o.z = v.z * inv; o.w = v.w * inv;
  *(float4*)(p + tid * 4) = o;
}

extern "C" void kernel_launch(void* const* d_in, const int* in_sizes, int n_in,
                              void* d_out, int out_size, void* d_ws, size_t ws_size,
                              hipStream_t stream) {
  const int* captions = (const int*)d_in[0];
  const float* H = (const float*)d_in[1];
  const int* targets = (const int*)d_in[2];
  const float* mask = (const float*)d_in[3];
  const float* Wa = (const float*)d_in[4];
  const float* Wc = (const float*)d_in[5];
  const float* fcw = (const float*)d_in[6];
  const float* fcb = (const float*)d_in[7];
  float* out = (float*)d_out;

  char* ws = (char*)d_ws;
  bf16* EA = (bf16*)(ws);                        // 16 MB [32][256][1024]
  bf16* ECT = (bf16*)(ws + (16u << 20));         // 16 MB [32][1024][256]
  bf16* X = (bf16*)(ws + (36u << 20));           // 32 MB [8192][2048]
  bf16* FW = (bf16*)(ws + (68u << 20));          //  4 MB [1024][2048]

  k1_prep<<<19456, 256, 0, stream>>>(captions, Wa, H, fcw, targets, Wc,
                                     EA, X, FW, ECT);
  k23_scores_pv<<<256, 256, 0, stream>>>(X, EA, ECT, mask);
  k4_fc<<<256, 512, 0, stream>>>(X, FW, fcb, out);
  k5_norm<<<8192, 256, 0, stream>>>(out);
}

// Round 12
// 104.171 us; speedup vs baseline: 1.2399x; 1.0528x over previous
//
#include <hip/hip_runtime.h>
#include <hip/hip_bf16.h>

typedef __attribute__((ext_vector_type(8))) short short8;   // 8 x bf16 (4 VGPRs)
typedef __attribute__((ext_vector_type(4))) float f32x4;
using bf16 = __hip_bfloat16;

// Problem sizes: B=32, LQ=LKV=256, HID=1024, EMB=1024, K_fc=2048

#define VMCNT(n) asm volatile("s_waitcnt vmcnt(" #n ")" ::: "memory")
#define LGK0     asm volatile("s_waitcnt lgkmcnt(0)" ::: "memory")
#define SBAR     __builtin_amdgcn_sched_barrier(0)

__device__ __forceinline__ void glds16(const void* g, void* lds) {
  __builtin_amdgcn_global_load_lds(
      (const __attribute__((address_space(1))) void*)g,
      (__attribute__((address_space(3))) void*)lds, 16, 0, 0);
}

__device__ __forceinline__ void barrier_raw() {
  asm volatile("" ::: "memory");
  __builtin_amdgcn_s_barrier();
  asm volatile("" ::: "memory");
}

// ---------------- K1: gathers + f32->bf16 conversions (merged) ----------------
__global__ __launch_bounds__(256) void k1_prep(
    const int* __restrict__ captions, const float* __restrict__ Wa,
    const float* __restrict__ H, const float* __restrict__ fcw,
    const int* __restrict__ targets, const float* __restrict__ Wc,
    bf16* __restrict__ EA, bf16* __restrict__ X, bf16* __restrict__ FW,
    bf16* __restrict__ ECT) {
  __shared__ float T[64][67];
  int task = blockIdx.x;
  int tid = threadIdx.x;
  if (task < 17408) {
    const float* src;
    bf16* dst;
    int n;
    if (task < 8192) {
      src = Wa + (size_t)captions[task] * 1024;
      dst = EA + (size_t)task * 1024;
      n = 1024;
    } else if (task < 16384) {
      int t = task - 8192;
      src = H + (size_t)t * 1024;
      dst = X + (size_t)t * 2048;
      n = 1024;
    } else {
      int t = task - 16384;
      src = fcw + (size_t)t * 2048;
      dst = FW + (size_t)t * 2048;
      n = 2048;
    }
    for (int c = tid * 4; c < n; c += 1024) {
      float4 v = *(const float4*)(src + c);
      __hip_bfloat162 p0, p1;
      p0.x = __float2bfloat16(v.x); p0.y = __float2bfloat16(v.y);
      p1.x = __float2bfloat16(v.z); p1.y = __float2bfloat16(v.w);
      *(__hip_bfloat162*)(dst + c) = p0;
      *(__hip_bfloat162*)(dst + c + 2) = p1;
    }
    return;
  }
  int bid = task - 17408;
  int b = bid >> 6;
  int kt = (bid >> 4) & 3;
  int ht = bid & 15;
#pragma unroll
  for (int p = 0; p < 4; ++p) {
    int k = p * 16 + (tid >> 4);
    int idx = targets[b * 256 + kt * 64 + k];
    const float* s = Wc + (size_t)idx * 1024 + ht * 64 + (tid & 15) * 4;
    float4 v = *(const float4*)s;
    int c = (tid & 15) * 4;
    T[k][c] = v.x; T[k][c + 1] = v.y; T[k][c + 2] = v.z; T[k][c + 3] = v.w;
  }
  __syncthreads();
#pragma unroll
  for (int p = 0; p < 8; ++p) {
    int h = p * 8 + (tid >> 5);
    int k = (tid & 31) * 2;
    __hip_bfloat162 o;
    o.x = __float2bfloat16(T[k][h]);
    o.y = __float2bfloat16(T[k + 1][h]);
    *(__hip_bfloat162*)(ECT + ((size_t)b * 1024 + ht * 64 + h) * 256 + kt * 64 + k) = o;
  }
}

// ---------------- K23: fused scores + masked-exp softmax + PV ----------------
// Scores K-loop now uses the R11-validated counted-vmcnt skeleton: 3 static
// buffers (literal pointers, no PHI), 2 tiles prefetch-ahead, 9 loads/stage
// -> VMCNT(18) steady / 9 / 0 epilogue; release = LGK0 + sched_barrier + bar.
// Softmax + PV unchanged (PV sync-only dbuf; big region re-aliased after
// scores' final VMCNT(0) + barriers).
__device__ __forceinline__ void k23_sstage(const bf16* __restrict__ Ag,
                                           const bf16* __restrict__ Bg, int kt,
                                           bf16* buf, int tid, int w) {
  {
    int row = tid >> 3, ss = (tid & 7) ^ (row & 7);
    glds16(Ag + (size_t)row * 2048 + kt * 64 + ss * 8,
           buf + (size_t)w * 64 * 8);                       // A: 32x64 (4 KB)
  }
#pragma unroll
  for (int i = 0; i < 8; ++i) {
    int c = i * 256 + tid;
    int row = c >> 3, ss = (c & 7) ^ (row & 7);
    glds16(Bg + (size_t)row * 1024 + kt * 64 + ss * 8,
           buf + 2048 + (size_t)(i * 256 + w * 64) * 8);    // B: 256x64 (32 KB)
  }
}

__device__ __forceinline__ void k23_stile(const bf16* buf, int w, int l,
                                          f32x4 (&sacc)[2][4]) {
  const bf16* As = buf;
  const bf16* Bs = buf + 2048;
#pragma unroll
  for (int kk = 0; kk < 2; ++kk) {
    short8 a2[2];
#pragma unroll
    for (int m2 = 0; m2 < 2; ++m2) {
      int ar = m2 * 16 + (l & 15);
      int sl = kk * 4 + (l >> 4);
      a2[m2] = *(const short8*)(As + ar * 64 + ((sl ^ (ar & 7)) * 8));
    }
    __builtin_amdgcn_s_setprio(1);
#pragma unroll
    for (int n = 0; n < 4; ++n) {
      int rb = w * 64 + n * 16 + (l & 15);
      int sl = kk * 4 + (l >> 4);
      short8 bfr = *(const short8*)(Bs + rb * 64 + ((sl ^ (rb & 7)) * 8));
#pragma unroll
      for (int m2 = 0; m2 < 2; ++m2)
        sacc[m2][n] = __builtin_amdgcn_mfma_f32_16x16x32_bf16(
            a2[m2], bfr, sacc[m2][n], 0, 0, 0);
    }
    __builtin_amdgcn_s_setprio(0);
  }
}

__global__ __launch_bounds__(256, 1) void k23_scores_pv(
    bf16* __restrict__ X, const bf16* __restrict__ EA,
    const bf16* __restrict__ ECT, const float* __restrict__ mask) {
  __shared__ __align__(16) char smem[16 * 1024 + 512 + 128 * 1024];
  bf16* p_lds = (bf16*)smem;                    // [32][256] swizzled
  float* red  = (float*)(smem + 16 * 1024);     // [4][32]
  bf16* big   = (bf16*)(smem + 16 * 1024 + 512);// 128KB: scores 3-buf / PV B2

  int p = blockIdx.x;
  int wg = (p & 7) * 32 + (p >> 3);   // chunked XCD swizzle (256 % 8 == 0)
  int b = wg >> 3;
  int mb = wg & 7;
  int tid = threadIdx.x, w = tid >> 6, l = tid & 63;

  const bf16* Ag = X + ((size_t)b * 256 + mb * 32) * 2048;
  const bf16* Bg = EA + (size_t)b * 256 * 1024;
  // three literal scores buffers (36 KB each; no pointer rotation)
  bf16* S0 = big;
  bf16* S1 = big + 18432;
  bf16* S2 = big + 36864;

  f32x4 sacc[2][4];
  f32x4 zero = {0.f, 0.f, 0.f, 0.f};
#pragma unroll
  for (int m2 = 0; m2 < 2; ++m2)
#pragma unroll
    for (int n = 0; n < 4; ++n) sacc[m2][n] = zero;

  // prologue: tiles 0,1 (18 loads in flight)
  k23_sstage(Ag, Bg, 0, S0, tid, w);
  k23_sstage(Ag, Bg, 1, S1, tid, w);

#define SBODY(T, C, S)                                \
  k23_sstage(Ag, Bg, (T) + 2, S, tid, w);             \
  VMCNT(18); SBAR;                                    \
  barrier_raw(); SBAR;                                \
  k23_stile(C, w, l, sacc);                           \
  LGK0; SBAR;                                         \
  barrier_raw();

  for (int tt = 0; tt < 12; tt += 3) {
    SBODY(tt + 0, S0, S2)
    SBODY(tt + 1, S1, S0)
    SBODY(tt + 2, S2, S1)
  }
  SBODY(12, S0, S2)
  SBODY(13, S1, S0)
#undef SBODY
  // t = 14 (S2; tile 15's 9 loads still in flight)
  VMCNT(9); SBAR;
  barrier_raw(); SBAR;
  k23_stile(S2, w, l, sacc);
  LGK0; SBAR;
  barrier_raw();
  // t = 15 (S0)
  VMCNT(0); SBAR;
  barrier_raw(); SBAR;
  k23_stile(S0, w, l, sacc);

  // ---- masked-exp softmax ----
  const float* mrow = mask + ((size_t)b * 256 + mb * 32) * 256;
  float s[2][4] = {{0.f, 0.f, 0.f, 0.f}, {0.f, 0.f, 0.f, 0.f}};
#pragma unroll
  for (int m2 = 0; m2 < 2; ++m2)
#pragma unroll
    for (int n = 0; n < 4; ++n)
#pragma unroll
      for (int i = 0; i < 4; ++i) {
        int r = m2 * 16 + ((l >> 4) << 2) + i;
        int c = w * 64 + n * 16 + (l & 15);
        float mv = mrow[r * 256 + c];
        mv = fminf(fmaxf(mv, 0.f), 1.f);
        float ev = expf(sacc[m2][n][i]) * mv;
        sacc[m2][n][i] = ev;
        s[m2][i] += ev;
      }
#pragma unroll
  for (int msk = 1; msk < 16; msk <<= 1)
#pragma unroll
    for (int m2 = 0; m2 < 2; ++m2)
#pragma unroll
      for (int i = 0; i < 4; ++i) s[m2][i] += __shfl_xor(s[m2][i], msk, 64);
  if ((l & 15) == 0) {
#pragma unroll
    for (int m2 = 0; m2 < 2; ++m2)
#pragma unroll
      for (int i = 0; i < 4; ++i)
        red[w * 32 + m2 * 16 + ((l >> 4) << 2) + i] = s[m2][i];
  }
  __syncthreads();
  float inv[2][4];
#pragma unroll
  for (int m2 = 0; m2 < 2; ++m2)
#pragma unroll
    for (int i = 0; i < 4; ++i) {
      int r = m2 * 16 + ((l >> 4) << 2) + i;
      float tot = red[r] + red[32 + r] + red[64 + r] + red[96 + r];
      inv[m2][i] = 1.f / (tot + 1e-10f);
    }
#pragma unroll
  for (int m2 = 0; m2 < 2; ++m2)
#pragma unroll
    for (int n = 0; n < 4; ++n)
#pragma unroll
      for (int i = 0; i < 4; ++i) {
        int r = m2 * 16 + ((l >> 4) << 2) + i;
        int c = w * 64 + n * 16 + (l & 15);
        float pv = sacc[m2][n][i] * inv[m2][i];
        p_lds[r * 256 + (((c >> 3) ^ (r & 7)) << 3) + (c & 7)] =
            __float2bfloat16(pv);
      }
  __syncthreads();

  // ---- PV: o = P @ EC (sync-only dbuf, unchanged) ----
  bf16* XO = X + ((size_t)b * 256 + mb * 32) * 2048 + 1024;
  for (int np = 0; np < 2; ++np) {
    f32x4 acc[2][8];
#pragma unroll
    for (int m2 = 0; m2 < 2; ++m2)
#pragma unroll
      for (int n = 0; n < 8; ++n) acc[m2][n] = zero;

#pragma unroll
    for (int it = 0; it < 16; ++it) {
      int g = it * 64 + l;
      int row = g >> 3, ss = (g & 7) ^ (row & 7);
      glds16(ECT + ((size_t)b * 1024 + np * 512 + w * 128 + row) * 256 + ss * 8,
             big + (size_t)(0 * 4 + w) * 8192 + (size_t)it * 512);
    }
    __syncthreads();
    for (int kt = 0; kt < 4; ++kt) {
      int cur = kt & 1;
      if (kt < 3) {
#pragma unroll
        for (int it = 0; it < 16; ++it) {
          int g = it * 64 + l;
          int row = g >> 3, ss = (g & 7) ^ (row & 7);
          glds16(ECT + ((size_t)b * 1024 + np * 512 + w * 128 + row) * 256 +
                     (kt + 1) * 64 + ss * 8,
                 big + (size_t)((cur ^ 1) * 4 + w) * 8192 + (size_t)it * 512);
        }
      }
      const bf16* Bw = big + (size_t)(cur * 4 + w) * 8192;
#pragma unroll
      for (int kk = 0; kk < 2; ++kk) {
        short8 a2[2];
#pragma unroll
        for (int m2 = 0; m2 < 2; ++m2) {
          int ar = m2 * 16 + (l & 15);
          int sl = kt * 8 + kk * 4 + (l >> 4);
          a2[m2] = *(const short8*)(p_lds + ar * 256 + ((sl ^ (ar & 7)) * 8));
        }
        __builtin_amdgcn_s_setprio(1);
#pragma unroll
        for (int n = 0; n < 8; ++n) {
          int rb = n * 16 + (l & 15);
          int sl = kk * 4 + (l >> 4);
          short8 bfr = *(const short8*)(Bw + rb * 64 + ((sl ^ (rb & 7)) * 8));
#pragma unroll
          for (int m2 = 0; m2 < 2; ++m2)
            acc[m2][n] = __builtin_amdgcn_mfma_f32_16x16x32_bf16(
                a2[m2], bfr, acc[m2][n], 0, 0, 0);
        }
        __builtin_amdgcn_s_setprio(0);
      }
      __syncthreads();
    }
#pragma unroll
    for (int m2 = 0; m2 < 2; ++m2)
#pragma unroll
      for (int n = 0; n < 8; ++n) {
        int rl = m2 * 16 + ((l >> 4) << 2);
        int col = np * 512 + w * 128 + n * 16 + (l & 15);
#pragma unroll
        for (int i = 0; i < 4; ++i)
          XO[(size_t)(rl + i) * 2048 + col] = __float2bfloat16(acc[m2][n][i]);
      }
  }
}

// ---------------- K4: out = X @ FW^T + fc_b + 1e-10 (f32) ----------------
// R11-proven counted-vmcnt triple-buffer pipeline (static L[3], literal
// indices, no pointer PHIs). Frozen.
#define K4E (256 * 64 + 128 * 64)   // elems per buffer: A 256x64 | B 128x64

__device__ __forceinline__ void k4_stage(const bf16* __restrict__ Ag,
                                         const bf16* __restrict__ Bg, int kt,
                                         bf16* Lb, int tid, int w) {
#pragma unroll
  for (int i = 0; i < 4; ++i) {            // A: 256 rows x 64 k = 32 KB
    int c = i * 512 + tid;
    int row = c >> 3, ss = (c & 7) ^ (row & 7);
    glds16(Ag + (size_t)row * 2048 + kt * 64 + ss * 8,
           Lb + (size_t)(i * 512 + w * 64) * 8);
  }
#pragma unroll
  for (int i = 0; i < 2; ++i) {            // B: 128 rows x 64 k = 16 KB
    int c = i * 512 + tid;
    int row = c >> 3, ss = (c & 7) ^ (row & 7);
    glds16(Bg + (size_t)row * 2048 + kt * 64 + ss * 8,
           Lb + (size_t)(256 * 64 + (i * 512 + w * 64) * 8));
  }
}

__device__ __forceinline__ void k4_tile(const bf16* Lb, int wr, int wc, int l,
                                        f32x4 (&acc)[4][4]) {
  const bf16* As = Lb;
  const bf16* Bs = Lb + 256 * 64;
  short8 a[2][4], b[2][4];
#pragma unroll
  for (int kk = 0; kk < 2; ++kk)
#pragma unroll
    for (int n = 0; n < 4; ++n) {
      int row = wc * 64 + n * 16 + (l & 15);
      int slot = kk * 4 + (l >> 4);
      b[kk][n] = *(const short8*)(Bs + row * 64 + ((slot ^ (row & 7)) * 8));
    }
#pragma unroll
  for (int kk = 0; kk < 2; ++kk)
#pragma unroll
    for (int m = 0; m < 4; ++m) {
      int row = wr * 64 + m * 16 + (l & 15);
      int slot = kk * 4 + (l >> 4);
      a[kk][m] = *(const short8*)(As + row * 64 + ((slot ^ (row & 7)) * 8));
    }
  __builtin_amdgcn_s_setprio(1);
#pragma unroll
  for (int kk = 0; kk < 2; ++kk)
#pragma unroll
    for (int m = 0; m < 4; ++m)
#pragma unroll
      for (int n = 0; n < 4; ++n)
        acc[m][n] = __builtin_amdgcn_mfma_f32_16x16x32_bf16(
            a[kk][m], b[kk][n], acc[m][n], 0, 0, 0);
  __builtin_amdgcn_s_setprio(0);
}

__global__ __launch_bounds__(512, 1) void k4_fc(
    const bf16* __restrict__ X, const bf16* __restrict__ FW,
    const float* __restrict__ fcb, float* __restrict__ out) {
  __shared__ __align__(16) bf16 L[3][K4E];   // 144 KB, static -> addrspace(3)
  int p = blockIdx.x;
  int wg = (p & 7) * 32 + (p >> 3);   // chunked XCD swizzle (256 % 8 == 0)
  int mb = wg >> 3;   // 0..31
  int nb = wg & 7;    // 0..7
  int tid = threadIdx.x, w = tid >> 6, l = tid & 63;
  int wr = w >> 1, wc = w & 1;
  f32x4 acc[4][4];
  f32x4 zero = {0.f, 0.f, 0.f, 0.f};
#pragma unroll
  for (int m = 0; m < 4; ++m)
#pragma unroll
    for (int n = 0; n < 4; ++n) acc[m][n] = zero;

  const bf16* Ag = X + (size_t)mb * 256 * 2048;
  const bf16* Bg = FW + (size_t)nb * 128 * 2048;

  k4_stage(Ag, Bg, 0, L[0], tid, w);
  k4_stage(Ag, Bg, 1, L[1], tid, w);

#define K4_BODY(T, C, S)                                   \
  k4_stage(Ag, Bg, (T) + 2, L[S], tid, w);                 \
  VMCNT(12); SBAR;                                         \
  barrier_raw(); SBAR;                                     \
  k4_tile(L[C], wr, wc, l, acc);                           \
  LGK0; SBAR;                                              \
  barrier_raw();

  for (int tt = 0; tt < 30; tt += 3) {
    K4_BODY(tt + 0, 0, 2)
    K4_BODY(tt + 1, 1, 0)
    K4_BODY(tt + 2, 2, 1)
  }
#undef K4_BODY
  VMCNT(6); SBAR;
  barrier_raw(); SBAR;
  k4_tile(L[0], wr, wc, l, acc);
  LGK0; SBAR;
  barrier_raw();
  VMCNT(0); SBAR;
  barrier_raw(); SBAR;
  k4_tile(L[1], wr, wc, l, acc);

  float bias[4];
#pragma unroll
  for (int n = 0; n < 4; ++n)
    bias[n] = fcb[nb * 128 + wc * 64 + n * 16 + (l & 15)];
#pragma unroll
  for (int m = 0; m < 4; ++m) {
    int rbase = mb * 256 + wr * 64 + m * 16 + ((l >> 4) << 2);
#pragma unroll
    for (int n = 0; n < 4; ++n) {
      int col = nb * 128 + wc * 64 + n * 16 + (l & 15);
#pragma unroll
      for (int i = 0; i < 4; ++i)
        out[(size_t)(rbase + i) * 1024 + col] = acc[m][n][i] + bias[n] + 1e-10f;
    }
  }
}

// ---------------- K5: in-place row L2 normalize ----------------
__global__ __launch_bounds__(256) void k5_norm(float* __restrict__ y) {
  __shared__ float red[4];
  int row = blockIdx.x;
  float* p = y + (size_t)row * 1024;
  int tid = threadIdx.x;
  float4 v = *(const float4*)(p + tid * 4);
  float ss = v.x * v.x + v.y * v.y + v.z * v.z + v.w * v.w;
#pragma unroll
  for (int m = 1; m < 64; m <<= 1) ss += __shfl_xor(ss, m, 64);
  if ((tid & 63) == 0) red[tid >> 6] = ss;
  __syncthreads();
  float tot = red[0] + red[1] + red[2] + red[3];
  float inv = 1.f / (sqrtf(tot) + 1e-8f);
  float4 o;
  o.x = v.x * inv; o.y = v.y * inv; o.z = v.z * inv; o.w = v.w * inv;
  *(float4*)(p + tid * 4) = o;
}

extern "C" void kernel_launch(void* const* d_in, const int* in_sizes, int n_in,
                              void* d_out, int out_size, void* d_ws, size_t ws_size,
                              hipStream_t stream) {
  const int* captions = (const int*)d_in[0];
  const float* H = (const float*)d_in[1];
  const int* targets = (const int*)d_in[2];
  const float* mask = (const float*)d_in[3];
  const float* Wa = (const float*)d_in[4];
  const float* Wc = (const float*)d_in[5];
  const float* fcw = (const float*)d_in[6];
  const float* fcb = (const float*)d_in[7];
  float* out = (float*)d_out;

  char* ws = (char*)d_ws;
  bf16* EA = (bf16*)(ws);                        // 16 MB [32][256][1024]
  bf16* ECT = (bf16*)(ws + (16u << 20));         // 16 MB [32][1024][256]
  bf16* X = (bf16*)(ws + (36u << 20));           // 32 MB [8192][2048]
  bf16* FW = (bf16*)(ws + (68u << 20));          //  4 MB [1024][2048]

  k1_prep<<<19456, 256, 0, stream>>>(captions, Wa, H, fcw, targets, Wc,
                                     EA, X, FW, ECT);
  k23_scores_pv<<<256, 256, 0, stream>>>(X, EA, ECT, mask);
  k4_fc<<<256, 512, 0, stream>>>(X, FW, fcb, out);
  k5_norm<<<8192, 256, 0, stream>>>(out);
}

// Round 13
// 103.633 us; speedup vs baseline: 1.2464x; 1.0052x over previous
//
#include <hip/hip_runtime.h>
#include <hip/hip_bf16.h>

typedef __attribute__((ext_vector_type(8))) short short8;   // 8 x bf16 (4 VGPRs)
typedef __attribute__((ext_vector_type(4))) float f32x4;
using bf16 = __hip_bfloat16;

// Problem sizes: B=32, LQ=LKV=256, HID=1024, EMB=1024, K_fc=2048

#define VMCNT(n) asm volatile("s_waitcnt vmcnt(" #n ")" ::: "memory")
#define LGK0     asm volatile("s_waitcnt lgkmcnt(0)" ::: "memory")
#define SBAR     __builtin_amdgcn_sched_barrier(0)

__device__ __forceinline__ void glds16(const void* g, void* lds) {
  __builtin_amdgcn_global_load_lds(
      (const __attribute__((address_space(1))) void*)g,
      (__attribute__((address_space(3))) void*)lds, 16, 0, 0);
}

__device__ __forceinline__ void barrier_raw() {
  asm volatile("" ::: "memory");
  __builtin_amdgcn_s_barrier();
  asm volatile("" ::: "memory");
}

// ---------------- K1: gathers + f32->bf16 conversions (merged) ----------------
__global__ __launch_bounds__(256) void k1_prep(
    const int* __restrict__ captions, const float* __restrict__ Wa,
    const float* __restrict__ H, const float* __restrict__ fcw,
    const int* __restrict__ targets, const float* __restrict__ Wc,
    bf16* __restrict__ EA, bf16* __restrict__ X, bf16* __restrict__ FW,
    bf16* __restrict__ ECT) {
  __shared__ float T[64][67];
  int task = blockIdx.x;
  int tid = threadIdx.x;
  if (task < 17408) {
    const float* src;
    bf16* dst;
    int n;
    if (task < 8192) {
      src = Wa + (size_t)captions[task] * 1024;
      dst = EA + (size_t)task * 1024;
      n = 1024;
    } else if (task < 16384) {
      int t = task - 8192;
      src = H + (size_t)t * 1024;
      dst = X + (size_t)t * 2048;
      n = 1024;
    } else {
      int t = task - 16384;
      src = fcw + (size_t)t * 2048;
      dst = FW + (size_t)t * 2048;
      n = 2048;
    }
    for (int c = tid * 4; c < n; c += 1024) {
      float4 v = *(const float4*)(src + c);
      __hip_bfloat162 p0, p1;
      p0.x = __float2bfloat16(v.x); p0.y = __float2bfloat16(v.y);
      p1.x = __float2bfloat16(v.z); p1.y = __float2bfloat16(v.w);
      *(__hip_bfloat162*)(dst + c) = p0;
      *(__hip_bfloat162*)(dst + c + 2) = p1;
    }
    return;
  }
  int bid = task - 17408;
  int b = bid >> 6;
  int kt = (bid >> 4) & 3;
  int ht = bid & 15;
#pragma unroll
  for (int p = 0; p < 4; ++p) {
    int k = p * 16 + (tid >> 4);
    int idx = targets[b * 256 + kt * 64 + k];
    const float* s = Wc + (size_t)idx * 1024 + ht * 64 + (tid & 15) * 4;
    float4 v = *(const float4*)s;
    int c = (tid & 15) * 4;
    T[k][c] = v.x; T[k][c + 1] = v.y; T[k][c + 2] = v.z; T[k][c + 3] = v.w;
  }
  __syncthreads();
#pragma unroll
  for (int p = 0; p < 8; ++p) {
    int h = p * 8 + (tid >> 5);
    int k = (tid & 31) * 2;
    __hip_bfloat162 o;
    o.x = __float2bfloat16(T[k][h]);
    o.y = __float2bfloat16(T[k + 1][h]);
    *(__hip_bfloat162*)(ECT + ((size_t)b * 1024 + ht * 64 + h) * 256 + kt * 64 + k) = o;
  }
}

// ---------------- K23: fused scores + masked-exp softmax + PV ----------------
// R12-proven: scores K-loop on the counted-vmcnt 3-buffer skeleton. Frozen.
__device__ __forceinline__ void k23_sstage(const bf16* __restrict__ Ag,
                                           const bf16* __restrict__ Bg, int kt,
                                           bf16* buf, int tid, int w) {
  {
    int row = tid >> 3, ss = (tid & 7) ^ (row & 7);
    glds16(Ag + (size_t)row * 2048 + kt * 64 + ss * 8,
           buf + (size_t)w * 64 * 8);                       // A: 32x64 (4 KB)
  }
#pragma unroll
  for (int i = 0; i < 8; ++i) {
    int c = i * 256 + tid;
    int row = c >> 3, ss = (c & 7) ^ (row & 7);
    glds16(Bg + (size_t)row * 1024 + kt * 64 + ss * 8,
           buf + 2048 + (size_t)(i * 256 + w * 64) * 8);    // B: 256x64 (32 KB)
  }
}

__device__ __forceinline__ void k23_stile(const bf16* buf, int w, int l,
                                          f32x4 (&sacc)[2][4]) {
  const bf16* As = buf;
  const bf16* Bs = buf + 2048;
#pragma unroll
  for (int kk = 0; kk < 2; ++kk) {
    short8 a2[2];
#pragma unroll
    for (int m2 = 0; m2 < 2; ++m2) {
      int ar = m2 * 16 + (l & 15);
      int sl = kk * 4 + (l >> 4);
      a2[m2] = *(const short8*)(As + ar * 64 + ((sl ^ (ar & 7)) * 8));
    }
    __builtin_amdgcn_s_setprio(1);
#pragma unroll
    for (int n = 0; n < 4; ++n) {
      int rb = w * 64 + n * 16 + (l & 15);
      int sl = kk * 4 + (l >> 4);
      short8 bfr = *(const short8*)(Bs + rb * 64 + ((sl ^ (rb & 7)) * 8));
#pragma unroll
      for (int m2 = 0; m2 < 2; ++m2)
        sacc[m2][n] = __builtin_amdgcn_mfma_f32_16x16x32_bf16(
            a2[m2], bfr, sacc[m2][n], 0, 0, 0);
    }
    __builtin_amdgcn_s_setprio(0);
  }
}

__global__ __launch_bounds__(256, 1) void k23_scores_pv(
    bf16* __restrict__ X, const bf16* __restrict__ EA,
    const bf16* __restrict__ ECT, const float* __restrict__ mask) {
  __shared__ __align__(16) char smem[16 * 1024 + 512 + 128 * 1024];
  bf16* p_lds = (bf16*)smem;                    // [32][256] swizzled
  float* red  = (float*)(smem + 16 * 1024);     // [4][32]
  bf16* big   = (bf16*)(smem + 16 * 1024 + 512);// 128KB: scores 3-buf / PV B2

  int p = blockIdx.x;
  int wg = (p & 7) * 32 + (p >> 3);   // chunked XCD swizzle (256 % 8 == 0)
  int b = wg >> 3;
  int mb = wg & 7;
  int tid = threadIdx.x, w = tid >> 6, l = tid & 63;

  const bf16* Ag = X + ((size_t)b * 256 + mb * 32) * 2048;
  const bf16* Bg = EA + (size_t)b * 256 * 1024;
  bf16* S0 = big;
  bf16* S1 = big + 18432;
  bf16* S2 = big + 36864;

  f32x4 sacc[2][4];
  f32x4 zero = {0.f, 0.f, 0.f, 0.f};
#pragma unroll
  for (int m2 = 0; m2 < 2; ++m2)
#pragma unroll
    for (int n = 0; n < 4; ++n) sacc[m2][n] = zero;

  k23_sstage(Ag, Bg, 0, S0, tid, w);
  k23_sstage(Ag, Bg, 1, S1, tid, w);

#define SBODY(T, C, S)                                \
  k23_sstage(Ag, Bg, (T) + 2, S, tid, w);             \
  VMCNT(18); SBAR;                                    \
  barrier_raw(); SBAR;                                \
  k23_stile(C, w, l, sacc);                           \
  LGK0; SBAR;                                         \
  barrier_raw();

  for (int tt = 0; tt < 12; tt += 3) {
    SBODY(tt + 0, S0, S2)
    SBODY(tt + 1, S1, S0)
    SBODY(tt + 2, S2, S1)
  }
  SBODY(12, S0, S2)
  SBODY(13, S1, S0)
#undef SBODY
  VMCNT(9); SBAR;
  barrier_raw(); SBAR;
  k23_stile(S2, w, l, sacc);
  LGK0; SBAR;
  barrier_raw();
  VMCNT(0); SBAR;
  barrier_raw(); SBAR;
  k23_stile(S0, w, l, sacc);

  // ---- masked-exp softmax ----
  const float* mrow = mask + ((size_t)b * 256 + mb * 32) * 256;
  float s[2][4] = {{0.f, 0.f, 0.f, 0.f}, {0.f, 0.f, 0.f, 0.f}};
#pragma unroll
  for (int m2 = 0; m2 < 2; ++m2)
#pragma unroll
    for (int n = 0; n < 4; ++n)
#pragma unroll
      for (int i = 0; i < 4; ++i) {
        int r = m2 * 16 + ((l >> 4) << 2) + i;
        int c = w * 64 + n * 16 + (l & 15);
        float mv = mrow[r * 256 + c];
        mv = fminf(fmaxf(mv, 0.f), 1.f);
        float ev = expf(sacc[m2][n][i]) * mv;
        sacc[m2][n][i] = ev;
        s[m2][i] += ev;
      }
#pragma unroll
  for (int msk = 1; msk < 16; msk <<= 1)
#pragma unroll
    for (int m2 = 0; m2 < 2; ++m2)
#pragma unroll
      for (int i = 0; i < 4; ++i) s[m2][i] += __shfl_xor(s[m2][i], msk, 64);
  if ((l & 15) == 0) {
#pragma unroll
    for (int m2 = 0; m2 < 2; ++m2)
#pragma unroll
      for (int i = 0; i < 4; ++i)
        red[w * 32 + m2 * 16 + ((l >> 4) << 2) + i] = s[m2][i];
  }
  __syncthreads();
  float inv[2][4];
#pragma unroll
  for (int m2 = 0; m2 < 2; ++m2)
#pragma unroll
    for (int i = 0; i < 4; ++i) {
      int r = m2 * 16 + ((l >> 4) << 2) + i;
      float tot = red[r] + red[32 + r] + red[64 + r] + red[96 + r];
      inv[m2][i] = 1.f / (tot + 1e-10f);
    }
#pragma unroll
  for (int m2 = 0; m2 < 2; ++m2)
#pragma unroll
    for (int n = 0; n < 4; ++n)
#pragma unroll
      for (int i = 0; i < 4; ++i) {
        int r = m2 * 16 + ((l >> 4) << 2) + i;
        int c = w * 64 + n * 16 + (l & 15);
        float pv = sacc[m2][n][i] * inv[m2][i];
        p_lds[r * 256 + (((c >> 3) ^ (r & 7)) << 3) + (c & 7)] =
            __float2bfloat16(pv);
      }
  __syncthreads();

  // ---- PV: o = P @ EC (sync-only dbuf, unchanged) ----
  bf16* XO = X + ((size_t)b * 256 + mb * 32) * 2048 + 1024;
  for (int np = 0; np < 2; ++np) {
    f32x4 acc[2][8];
#pragma unroll
    for (int m2 = 0; m2 < 2; ++m2)
#pragma unroll
      for (int n = 0; n < 8; ++n) acc[m2][n] = zero;

#pragma unroll
    for (int it = 0; it < 16; ++it) {
      int g = it * 64 + l;
      int row = g >> 3, ss = (g & 7) ^ (row & 7);
      glds16(ECT + ((size_t)b * 1024 + np * 512 + w * 128 + row) * 256 + ss * 8,
             big + (size_t)(0 * 4 + w) * 8192 + (size_t)it * 512);
    }
    __syncthreads();
    for (int kt = 0; kt < 4; ++kt) {
      int cur = kt & 1;
      if (kt < 3) {
#pragma unroll
        for (int it = 0; it < 16; ++it) {
          int g = it * 64 + l;
          int row = g >> 3, ss = (g & 7) ^ (row & 7);
          glds16(ECT + ((size_t)b * 1024 + np * 512 + w * 128 + row) * 256 +
                     (kt + 1) * 64 + ss * 8,
                 big + (size_t)((cur ^ 1) * 4 + w) * 8192 + (size_t)it * 512);
        }
      }
      const bf16* Bw = big + (size_t)(cur * 4 + w) * 8192;
#pragma unroll
      for (int kk = 0; kk < 2; ++kk) {
        short8 a2[2];
#pragma unroll
        for (int m2 = 0; m2 < 2; ++m2) {
          int ar = m2 * 16 + (l & 15);
          int sl = kt * 8 + kk * 4 + (l >> 4);
          a2[m2] = *(const short8*)(p_lds + ar * 256 + ((sl ^ (ar & 7)) * 8));
        }
        __builtin_amdgcn_s_setprio(1);
#pragma unroll
        for (int n = 0; n < 8; ++n) {
          int rb = n * 16 + (l & 15);
          int sl = kk * 4 + (l >> 4);
          short8 bfr = *(const short8*)(Bw + rb * 64 + ((sl ^ (rb & 7)) * 8));
#pragma unroll
          for (int m2 = 0; m2 < 2; ++m2)
            acc[m2][n] = __builtin_amdgcn_mfma_f32_16x16x32_bf16(
                a2[m2], bfr, acc[m2][n], 0, 0, 0);
        }
        __builtin_amdgcn_s_setprio(0);
      }
      __syncthreads();
    }
#pragma unroll
    for (int m2 = 0; m2 < 2; ++m2)
#pragma unroll
      for (int n = 0; n < 8; ++n) {
        int rl = m2 * 16 + ((l >> 4) << 2);
        int col = np * 512 + w * 128 + n * 16 + (l & 15);
#pragma unroll
        for (int i = 0; i < 4; ++i)
          XO[(size_t)(rl + i) * 2048 + col] = __float2bfloat16(acc[m2][n][i]);
      }
  }
}

// ---------------- K4: out = X @ FW^T + fc_b + 1e-10 (f32) ----------------
// NEW: 128x128 tile, BK=64, 2 blocks/CU (64 KB LDS, grid 512, 256 thr,
// 4 waves 2x2, wave tile 64x64). Counted-vmcnt depth-1: stage(t+1) ->
// VMCNT(8) retires exactly tile-t's 8 loads; t+1's stay in flight ACROSS
// the barrier (unlike __syncthreads drain-to-0). Second co-resident block
// covers drain stalls. Static L[2], literal indices, no pointer PHIs
// (R11-validated discipline). Proven 8-slot XOR swizzle.
#define K4T (128 * 64)   // elems per operand (16 KB)

__device__ __forceinline__ void k4_stage(const bf16* __restrict__ Ag,
                                         const bf16* __restrict__ Bg, int kt,
                                         bf16* Lb, int tid, int w) {
#pragma unroll
  for (int i = 0; i < 4; ++i) {            // A: 128 rows x 64 k = 16 KB
    int c = i * 256 + tid;
    int row = c >> 3, ss = (c & 7) ^ (row & 7);
    glds16(Ag + (size_t)row * 2048 + kt * 64 + ss * 8,
           Lb + (size_t)(i * 256 + w * 64) * 8);
  }
#pragma unroll
  for (int i = 0; i < 4; ++i) {            // B: 128 rows x 64 k = 16 KB
    int c = i * 256 + tid;
    int row = c >> 3, ss = (c & 7) ^ (row & 7);
    glds16(Bg + (size_t)row * 2048 + kt * 64 + ss * 8,
           Lb + K4T + (size_t)(i * 256 + w * 64) * 8);
  }
}

__device__ __forceinline__ void k4_tile(const bf16* Lb, int wr, int wc, int l,
                                        f32x4 (&acc)[4][4]) {
  const bf16* As = Lb;
  const bf16* Bs = Lb + K4T;
  short8 a[2][4], b[2][4];
#pragma unroll
  for (int kk = 0; kk < 2; ++kk)
#pragma unroll
    for (int n = 0; n < 4; ++n) {
      int row = wc * 64 + n * 16 + (l & 15);
      int slot = kk * 4 + (l >> 4);
      b[kk][n] = *(const short8*)(Bs + row * 64 + ((slot ^ (row & 7)) * 8));
    }
#pragma unroll
  for (int kk = 0; kk < 2; ++kk)
#pragma unroll
    for (int m = 0; m < 4; ++m) {
      int row = wr * 64 + m * 16 + (l & 15);
      int slot = kk * 4 + (l >> 4);
      a[kk][m] = *(const short8*)(As + row * 64 + ((slot ^ (row & 7)) * 8));
    }
  __builtin_amdgcn_s_setprio(1);
#pragma unroll
  for (int kk = 0; kk < 2; ++kk)
#pragma unroll
    for (int m = 0; m < 4; ++m)
#pragma unroll
      for (int n = 0; n < 4; ++n)
        acc[m][n] = __builtin_amdgcn_mfma_f32_16x16x32_bf16(
            a[kk][m], b[kk][n], acc[m][n], 0, 0, 0);
  __builtin_amdgcn_s_setprio(0);
}

__global__ __launch_bounds__(256, 2) void k4_fc(
    const bf16* __restrict__ X, const bf16* __restrict__ FW,
    const float* __restrict__ fcb, float* __restrict__ out) {
  __shared__ __align__(16) bf16 L[2][2 * K4T];   // 64 KB -> 2 blocks/CU
  int p = blockIdx.x;
  int wg = (p & 7) * 64 + (p >> 3);   // chunked XCD swizzle (512 % 8 == 0)
  int mb = wg >> 3;   // 0..63
  int nb = wg & 7;    // 0..7
  int tid = threadIdx.x, w = tid >> 6, l = tid & 63;
  int wr = w >> 1, wc = w & 1;
  f32x4 acc[4][4];
  f32x4 zero = {0.f, 0.f, 0.f, 0.f};
#pragma unroll
  for (int m = 0; m < 4; ++m)
#pragma unroll
    for (int n = 0; n < 4; ++n) acc[m][n] = zero;

  const bf16* Ag = X + (size_t)mb * 128 * 2048;
  const bf16* Bg = FW + (size_t)nb * 128 * 2048;

  k4_stage(Ag, Bg, 0, L[0], tid, w);   // 8 loads in flight

#define K4_BODY(T, C, S)                                   \
  k4_stage(Ag, Bg, (T) + 1, L[S], tid, w);                 \
  VMCNT(8); SBAR;                                          \
  barrier_raw(); SBAR;                                     \
  k4_tile(L[C], wr, wc, l, acc);                           \
  LGK0; SBAR;                                              \
  barrier_raw();

  for (int tt = 0; tt < 30; tt += 2) {
    K4_BODY(tt + 0, 0, 1)
    K4_BODY(tt + 1, 1, 0)
  }
  // t = 30: stage tile 31 -> L[1], consume L[0]
  K4_BODY(30, 0, 1)
#undef K4_BODY
  // t = 31 (L[1]; its 8 loads still in flight)
  VMCNT(0); SBAR;
  barrier_raw(); SBAR;
  k4_tile(L[1], wr, wc, l, acc);

  float bias[4];
#pragma unroll
  for (int n = 0; n < 4; ++n)
    bias[n] = fcb[nb * 128 + wc * 64 + n * 16 + (l & 15)];
#pragma unroll
  for (int m = 0; m < 4; ++m) {
    int rbase = mb * 128 + wr * 64 + m * 16 + ((l >> 4) << 2);
#pragma unroll
    for (int n = 0; n < 4; ++n) {
      int col = nb * 128 + wc * 64 + n * 16 + (l & 15);
#pragma unroll
      for (int i = 0; i < 4; ++i)
        out[(size_t)(rbase + i) * 1024 + col] = acc[m][n][i] + bias[n] + 1e-10f;
    }
  }
}

// ---------------- K5: in-place row L2 normalize ----------------
__global__ __launch_bounds__(256) void k5_norm(float* __restrict__ y) {
  __shared__ float red[4];
  int row = blockIdx.x;
  float* p = y + (size_t)row * 1024;
  int tid = threadIdx.x;
  float4 v = *(const float4*)(p + tid * 4);
  float ss = v.x * v.x + v.y * v.y + v.z * v.z + v.w * v.w;
#pragma unroll
  for (int m = 1; m < 64; m <<= 1) ss += __shfl_xor(ss, m, 64);
  if ((tid & 63) == 0) red[tid >> 6] = ss;
  __syncthreads();
  float tot = red[0] + red[1] + red[2] + red[3];
  float inv = 1.f / (sqrtf(tot) + 1e-8f);
  float4 o;
  o.x = v.x * inv; o.y = v.y * inv; o.z = v.z * inv; o.w = v.w * inv;
  *(float4*)(p + tid * 4) = o;
}

extern "C" void kernel_launch(void* const* d_in, const int* in_sizes, int n_in,
                              void* d_out, int out_size, void* d_ws, size_t ws_size,
                              hipStream_t stream) {
  const int* captions = (const int*)d_in[0];
  const float* H = (const float*)d_in[1];
  const int* targets = (const int*)d_in[2];
  const float* mask = (const float*)d_in[3];
  const float* Wa = (const float*)d_in[4];
  const float* Wc = (const float*)d_in[5];
  const float* fcw = (const float*)d_in[6];
  const float* fcb = (const float*)d_in[7];
  float* out = (float*)d_out;

  char* ws = (char*)d_ws;
  bf16* EA = (bf16*)(ws);                        // 16 MB [32][256][1024]
  bf16* ECT = (bf16*)(ws + (16u << 20));         // 16 MB [32][1024][256]
  bf16* X = (bf16*)(ws + (36u << 20));           // 32 MB [8192][2048]
  bf16* FW = (bf16*)(ws + (68u << 20));          //  4 MB [1024][2048]

  k1_prep<<<19456, 256, 0, stream>>>(captions, Wa, H, fcw, targets, Wc,
                                     EA, X, FW, ECT);
  k23_scores_pv<<<256, 256, 0, stream>>>(X, EA, ECT, mask);
  k4_fc<<<512, 256, 0, stream>>>(X, FW, fcb, out);
  k5_norm<<<8192, 256, 0, stream>>>(out);
}

// Round 14
// 103.022 us; speedup vs baseline: 1.2538x; 1.0059x over previous
//
#include <hip/hip_runtime.h>
#include <hip/hip_bf16.h>

typedef __attribute__((ext_vector_type(8))) short short8;   // 8 x bf16 (4 VGPRs)
typedef __attribute__((ext_vector_type(4))) float f32x4;
using bf16 = __hip_bfloat16;

// Problem sizes: B=32, LQ=LKV=256, HID=1024, EMB=1024, K_fc=2048

#define VMCNT(n) asm volatile("s_waitcnt vmcnt(" #n ")" ::: "memory")
#define LGK0     asm volatile("s_waitcnt lgkmcnt(0)" ::: "memory")
#define SBAR     __builtin_amdgcn_sched_barrier(0)

__device__ __forceinline__ void glds16(const void* g, void* lds) {
  __builtin_amdgcn_global_load_lds(
      (const __attribute__((address_space(1))) void*)g,
      (__attribute__((address_space(3))) void*)lds, 16, 0, 0);
}

__device__ __forceinline__ void barrier_raw() {
  asm volatile("" ::: "memory");
  __builtin_amdgcn_s_barrier();
  asm volatile("" ::: "memory");
}

// ---------------- K1: gathers + f32->bf16 conversions (merged) ----------------
__global__ __launch_bounds__(256) void k1_prep(
    const int* __restrict__ captions, const float* __restrict__ Wa,
    const float* __restrict__ H, const float* __restrict__ fcw,
    const int* __restrict__ targets, const float* __restrict__ Wc,
    bf16* __restrict__ EA, bf16* __restrict__ X, bf16* __restrict__ FW,
    bf16* __restrict__ ECT) {
  __shared__ float T[64][67];
  int task = blockIdx.x;
  int tid = threadIdx.x;
  if (task < 17408) {
    const float* src;
    bf16* dst;
    int n;
    if (task < 8192) {
      src = Wa + (size_t)captions[task] * 1024;
      dst = EA + (size_t)task * 1024;
      n = 1024;
    } else if (task < 16384) {
      int t = task - 8192;
      src = H + (size_t)t * 1024;
      dst = X + (size_t)t * 2048;
      n = 1024;
    } else {
      int t = task - 16384;
      src = fcw + (size_t)t * 2048;
      dst = FW + (size_t)t * 2048;
      n = 2048;
    }
    for (int c = tid * 4; c < n; c += 1024) {
      float4 v = *(const float4*)(src + c);
      __hip_bfloat162 p0, p1;
      p0.x = __float2bfloat16(v.x); p0.y = __float2bfloat16(v.y);
      p1.x = __float2bfloat16(v.z); p1.y = __float2bfloat16(v.w);
      *(__hip_bfloat162*)(dst + c) = p0;
      *(__hip_bfloat162*)(dst + c + 2) = p1;
    }
    return;
  }
  int bid = task - 17408;
  int b = bid >> 6;
  int kt = (bid >> 4) & 3;
  int ht = bid & 15;
#pragma unroll
  for (int p = 0; p < 4; ++p) {
    int k = p * 16 + (tid >> 4);
    int idx = targets[b * 256 + kt * 64 + k];
    const float* s = Wc + (size_t)idx * 1024 + ht * 64 + (tid & 15) * 4;
    float4 v = *(const float4*)s;
    int c = (tid & 15) * 4;
    T[k][c] = v.x; T[k][c + 1] = v.y; T[k][c + 2] = v.z; T[k][c + 3] = v.w;
  }
  __syncthreads();
#pragma unroll
  for (int p = 0; p < 8; ++p) {
    int h = p * 8 + (tid >> 5);
    int k = (tid & 31) * 2;
    __hip_bfloat162 o;
    o.x = __float2bfloat16(T[k][h]);
    o.y = __float2bfloat16(T[k + 1][h]);
    *(__hip_bfloat162*)(ECT + ((size_t)b * 1024 + ht * 64 + h) * 256 + kt * 64 + k) = o;
  }
}

// ---------------- K23: fused scores + masked-exp softmax + PV ----------------
// R12-proven: scores K-loop on the counted-vmcnt 3-buffer skeleton. Frozen.
__device__ __forceinline__ void k23_sstage(const bf16* __restrict__ Ag,
                                           const bf16* __restrict__ Bg, int kt,
                                           bf16* buf, int tid, int w) {
  {
    int row = tid >> 3, ss = (tid & 7) ^ (row & 7);
    glds16(Ag + (size_t)row * 2048 + kt * 64 + ss * 8,
           buf + (size_t)w * 64 * 8);                       // A: 32x64 (4 KB)
  }
#pragma unroll
  for (int i = 0; i < 8; ++i) {
    int c = i * 256 + tid;
    int row = c >> 3, ss = (c & 7) ^ (row & 7);
    glds16(Bg + (size_t)row * 1024 + kt * 64 + ss * 8,
           buf + 2048 + (size_t)(i * 256 + w * 64) * 8);    // B: 256x64 (32 KB)
  }
}

__device__ __forceinline__ void k23_stile(const bf16* buf, int w, int l,
                                          f32x4 (&sacc)[2][4]) {
  const bf16* As = buf;
  const bf16* Bs = buf + 2048;
#pragma unroll
  for (int kk = 0; kk < 2; ++kk) {
    short8 a2[2];
#pragma unroll
    for (int m2 = 0; m2 < 2; ++m2) {
      int ar = m2 * 16 + (l & 15);
      int sl = kk * 4 + (l >> 4);
      a2[m2] = *(const short8*)(As + ar * 64 + ((sl ^ (ar & 7)) * 8));
    }
    __builtin_amdgcn_s_setprio(1);
#pragma unroll
    for (int n = 0; n < 4; ++n) {
      int rb = w * 64 + n * 16 + (l & 15);
      int sl = kk * 4 + (l >> 4);
      short8 bfr = *(const short8*)(Bs + rb * 64 + ((sl ^ (rb & 7)) * 8));
#pragma unroll
      for (int m2 = 0; m2 < 2; ++m2)
        sacc[m2][n] = __builtin_amdgcn_mfma_f32_16x16x32_bf16(
            a2[m2], bfr, sacc[m2][n], 0, 0, 0);
    }
    __builtin_amdgcn_s_setprio(0);
  }
}

__global__ __launch_bounds__(256, 1) void k23_scores_pv(
    bf16* __restrict__ X, const bf16* __restrict__ EA,
    const bf16* __restrict__ ECT, const float* __restrict__ mask) {
  __shared__ __align__(16) char smem[16 * 1024 + 512 + 128 * 1024];
  bf16* p_lds = (bf16*)smem;                    // [32][256] swizzled
  float* red  = (float*)(smem + 16 * 1024);     // [4][32]
  bf16* big   = (bf16*)(smem + 16 * 1024 + 512);// 128KB: scores 3-buf / PV B2

  int p = blockIdx.x;
  int wg = (p & 7) * 32 + (p >> 3);   // chunked XCD swizzle (256 % 8 == 0)
  int b = wg >> 3;
  int mb = wg & 7;
  int tid = threadIdx.x, w = tid >> 6, l = tid & 63;

  const bf16* Ag = X + ((size_t)b * 256 + mb * 32) * 2048;
  const bf16* Bg = EA + (size_t)b * 256 * 1024;
  bf16* S0 = big;
  bf16* S1 = big + 18432;
  bf16* S2 = big + 36864;

  f32x4 sacc[2][4];
  f32x4 zero = {0.f, 0.f, 0.f, 0.f};
#pragma unroll
  for (int m2 = 0; m2 < 2; ++m2)
#pragma unroll
    for (int n = 0; n < 4; ++n) sacc[m2][n] = zero;

  k23_sstage(Ag, Bg, 0, S0, tid, w);
  k23_sstage(Ag, Bg, 1, S1, tid, w);

#define SBODY(T, C, S)                                \
  k23_sstage(Ag, Bg, (T) + 2, S, tid, w);             \
  VMCNT(18); SBAR;                                    \
  barrier_raw(); SBAR;                                \
  k23_stile(C, w, l, sacc);                           \
  LGK0; SBAR;                                         \
  barrier_raw();

  for (int tt = 0; tt < 12; tt += 3) {
    SBODY(tt + 0, S0, S2)
    SBODY(tt + 1, S1, S0)
    SBODY(tt + 2, S2, S1)
  }
  SBODY(12, S0, S2)
  SBODY(13, S1, S0)
#undef SBODY
  VMCNT(9); SBAR;
  barrier_raw(); SBAR;
  k23_stile(S2, w, l, sacc);
  LGK0; SBAR;
  barrier_raw();
  VMCNT(0); SBAR;
  barrier_raw(); SBAR;
  k23_stile(S0, w, l, sacc);

  // ---- masked-exp softmax ----
  const float* mrow = mask + ((size_t)b * 256 + mb * 32) * 256;
  float s[2][4] = {{0.f, 0.f, 0.f, 0.f}, {0.f, 0.f, 0.f, 0.f}};
#pragma unroll
  for (int m2 = 0; m2 < 2; ++m2)
#pragma unroll
    for (int n = 0; n < 4; ++n)
#pragma unroll
      for (int i = 0; i < 4; ++i) {
        int r = m2 * 16 + ((l >> 4) << 2) + i;
        int c = w * 64 + n * 16 + (l & 15);
        float mv = mrow[r * 256 + c];
        mv = fminf(fmaxf(mv, 0.f), 1.f);
        float ev = expf(sacc[m2][n][i]) * mv;
        sacc[m2][n][i] = ev;
        s[m2][i] += ev;
      }
#pragma unroll
  for (int msk = 1; msk < 16; msk <<= 1)
#pragma unroll
    for (int m2 = 0; m2 < 2; ++m2)
#pragma unroll
      for (int i = 0; i < 4; ++i) s[m2][i] += __shfl_xor(s[m2][i], msk, 64);
  if ((l & 15) == 0) {
#pragma unroll
    for (int m2 = 0; m2 < 2; ++m2)
#pragma unroll
      for (int i = 0; i < 4; ++i)
        red[w * 32 + m2 * 16 + ((l >> 4) << 2) + i] = s[m2][i];
  }
  __syncthreads();
  float inv[2][4];
#pragma unroll
  for (int m2 = 0; m2 < 2; ++m2)
#pragma unroll
    for (int i = 0; i < 4; ++i) {
      int r = m2 * 16 + ((l >> 4) << 2) + i;
      float tot = red[r] + red[32 + r] + red[64 + r] + red[96 + r];
      inv[m2][i] = 1.f / (tot + 1e-10f);
    }
#pragma unroll
  for (int m2 = 0; m2 < 2; ++m2)
#pragma unroll
    for (int n = 0; n < 4; ++n)
#pragma unroll
      for (int i = 0; i < 4; ++i) {
        int r = m2 * 16 + ((l >> 4) << 2) + i;
        int c = w * 64 + n * 16 + (l & 15);
        float pv = sacc[m2][n][i] * inv[m2][i];
        p_lds[r * 256 + (((c >> 3) ^ (r & 7)) << 3) + (c & 7)] =
            __float2bfloat16(pv);
      }
  __syncthreads();

  // ---- PV: o = P @ EC (sync-only dbuf, unchanged) ----
  bf16* XO = X + ((size_t)b * 256 + mb * 32) * 2048 + 1024;
  for (int np = 0; np < 2; ++np) {
    f32x4 acc[2][8];
#pragma unroll
    for (int m2 = 0; m2 < 2; ++m2)
#pragma unroll
      for (int n = 0; n < 8; ++n) acc[m2][n] = zero;

#pragma unroll
    for (int it = 0; it < 16; ++it) {
      int g = it * 64 + l;
      int row = g >> 3, ss = (g & 7) ^ (row & 7);
      glds16(ECT + ((size_t)b * 1024 + np * 512 + w * 128 + row) * 256 + ss * 8,
             big + (size_t)(0 * 4 + w) * 8192 + (size_t)it * 512);
    }
    __syncthreads();
    for (int kt = 0; kt < 4; ++kt) {
      int cur = kt & 1;
      if (kt < 3) {
#pragma unroll
        for (int it = 0; it < 16; ++it) {
          int g = it * 64 + l;
          int row = g >> 3, ss = (g & 7) ^ (row & 7);
          glds16(ECT + ((size_t)b * 1024 + np * 512 + w * 128 + row) * 256 +
                     (kt + 1) * 64 + ss * 8,
                 big + (size_t)((cur ^ 1) * 4 + w) * 8192 + (size_t)it * 512);
        }
      }
      const bf16* Bw = big + (size_t)(cur * 4 + w) * 8192;
#pragma unroll
      for (int kk = 0; kk < 2; ++kk) {
        short8 a2[2];
#pragma unroll
        for (int m2 = 0; m2 < 2; ++m2) {
          int ar = m2 * 16 + (l & 15);
          int sl = kt * 8 + kk * 4 + (l >> 4);
          a2[m2] = *(const short8*)(p_lds + ar * 256 + ((sl ^ (ar & 7)) * 8));
        }
        __builtin_amdgcn_s_setprio(1);
#pragma unroll
        for (int n = 0; n < 8; ++n) {
          int rb = n * 16 + (l & 15);
          int sl = kk * 4 + (l >> 4);
          short8 bfr = *(const short8*)(Bw + rb * 64 + ((sl ^ (rb & 7)) * 8));
#pragma unroll
          for (int m2 = 0; m2 < 2; ++m2)
            acc[m2][n] = __builtin_amdgcn_mfma_f32_16x16x32_bf16(
                a2[m2], bfr, acc[m2][n], 0, 0, 0);
        }
        __builtin_amdgcn_s_setprio(0);
      }
      __syncthreads();
    }
#pragma unroll
    for (int m2 = 0; m2 < 2; ++m2)
#pragma unroll
      for (int n = 0; n < 8; ++n) {
        int rl = m2 * 16 + ((l >> 4) << 2);
        int col = np * 512 + w * 128 + n * 16 + (l & 15);
#pragma unroll
        for (int i = 0; i < 4; ++i)
          XO[(size_t)(rl + i) * 2048 + col] = __float2bfloat16(acc[m2][n][i]);
      }
  }
}

// ---------------- K4: out = X @ FW^T + fc_b + 1e-10 (f32) ----------------
// 128x128 tile, 2 blocks/CU, counted-vmcnt — NOW with 2-phase split-issue:
// phase A: issue A-half of stage(t+1) (4 loads) -> VMCNT(4) retires exactly
// tile-t's 8 -> bar -> kk=0 reads+16 MFMA -> bar (phase alignment);
// phase B: issue B-half (4 loads) -> kk=1 reads+16 MFMA -> LGK0 -> bar.
// Spreads DMA issue across the tile and halves each LDS/MFMA burst so the
// two co-resident blocks' bursts overlap. Ledger by induction: 8 outstanding
// at each iteration entry. Static L[2], literal indices (R11 discipline).
#define K4T (128 * 64)   // elems per operand (16 KB)

__device__ __forceinline__ void k4_stageA(const bf16* __restrict__ Ag, int kt,
                                          bf16* Lb, int tid, int w) {
#pragma unroll
  for (int i = 0; i < 4; ++i) {            // A: 128 rows x 64 k = 16 KB
    int c = i * 256 + tid;
    int row = c >> 3, ss = (c & 7) ^ (row & 7);
    glds16(Ag + (size_t)row * 2048 + kt * 64 + ss * 8,
           Lb + (size_t)(i * 256 + w * 64) * 8);
  }
}

__device__ __forceinline__ void k4_stageB(const bf16* __restrict__ Bg, int kt,
                                          bf16* Lb, int tid, int w) {
#pragma unroll
  for (int i = 0; i < 4; ++i) {            // B: 128 rows x 64 k = 16 KB
    int c = i * 256 + tid;
    int row = c >> 3, ss = (c & 7) ^ (row & 7);
    glds16(Bg + (size_t)row * 2048 + kt * 64 + ss * 8,
           Lb + K4T + (size_t)(i * 256 + w * 64) * 8);
  }
}

__device__ __forceinline__ void k4_half(const bf16* Lb, int kk, int wr, int wc,
                                        int l, f32x4 (&acc)[4][4]) {
  const bf16* As = Lb;
  const bf16* Bs = Lb + K4T;
  short8 a[4], b[4];
#pragma unroll
  for (int n = 0; n < 4; ++n) {
    int row = wc * 64 + n * 16 + (l & 15);
    int slot = kk * 4 + (l >> 4);
    b[n] = *(const short8*)(Bs + row * 64 + ((slot ^ (row & 7)) * 8));
  }
#pragma unroll
  for (int m = 0; m < 4; ++m) {
    int row = wr * 64 + m * 16 + (l & 15);
    int slot = kk * 4 + (l >> 4);
    a[m] = *(const short8*)(As + row * 64 + ((slot ^ (row & 7)) * 8));
  }
  __builtin_amdgcn_s_setprio(1);
#pragma unroll
  for (int m = 0; m < 4; ++m)
#pragma unroll
    for (int n = 0; n < 4; ++n)
      acc[m][n] = __builtin_amdgcn_mfma_f32_16x16x32_bf16(
          a[m], b[n], acc[m][n], 0, 0, 0);
  __builtin_amdgcn_s_setprio(0);
}

__global__ __launch_bounds__(256, 2) void k4_fc(
    const bf16* __restrict__ X, const bf16* __restrict__ FW,
    const float* __restrict__ fcb, float* __restrict__ out) {
  __shared__ __align__(16) bf16 L[2][2 * K4T];   // 64 KB -> 2 blocks/CU
  int p = blockIdx.x;
  int wg = (p & 7) * 64 + (p >> 3);   // chunked XCD swizzle (512 % 8 == 0)
  int mb = wg >> 3;   // 0..63
  int nb = wg & 7;    // 0..7
  int tid = threadIdx.x, w = tid >> 6, l = tid & 63;
  int wr = w >> 1, wc = w & 1;
  f32x4 acc[4][4];
  f32x4 zero = {0.f, 0.f, 0.f, 0.f};
#pragma unroll
  for (int m = 0; m < 4; ++m)
#pragma unroll
    for (int n = 0; n < 4; ++n) acc[m][n] = zero;

  const bf16* Ag = X + (size_t)mb * 128 * 2048;
  const bf16* Bg = FW + (size_t)nb * 128 * 2048;

  k4_stageA(Ag, 0, L[0], tid, w);
  k4_stageB(Bg, 0, L[0], tid, w);      // 8 loads in flight

#define K4_BODY(T, C, S)                                   \
  k4_stageA(Ag, (T) + 1, L[S], tid, w);                    \
  VMCNT(4); SBAR;                                          \
  barrier_raw(); SBAR;                                     \
  k4_half(L[C], 0, wr, wc, l, acc);                        \
  barrier_raw(); SBAR;                                     \
  k4_stageB(Bg, (T) + 1, L[S], tid, w);                    \
  k4_half(L[C], 1, wr, wc, l, acc);                        \
  LGK0; SBAR;                                              \
  barrier_raw();

  for (int tt = 0; tt < 30; tt += 2) {
    K4_BODY(tt + 0, 0, 1)
    K4_BODY(tt + 1, 1, 0)
  }
  K4_BODY(30, 0, 1)
#undef K4_BODY
  // t = 31 (L[1]; its 8 loads still in flight)
  VMCNT(0); SBAR;
  barrier_raw(); SBAR;
  k4_half(L[1], 0, wr, wc, l, acc);
  k4_half(L[1], 1, wr, wc, l, acc);

  float bias[4];
#pragma unroll
  for (int n = 0; n < 4; ++n)
    bias[n] = fcb[nb * 128 + wc * 64 + n * 16 + (l & 15)];
#pragma unroll
  for (int m = 0; m < 4; ++m) {
    int rbase = mb * 128 + wr * 64 + m * 16 + ((l >> 4) << 2);
#pragma unroll
    for (int n = 0; n < 4; ++n) {
      int col = nb * 128 + wc * 64 + n * 16 + (l & 15);
#pragma unroll
      for (int i = 0; i < 4; ++i)
        out[(size_t)(rbase + i) * 1024 + col] = acc[m][n][i] + bias[n] + 1e-10f;
    }
  }
}

// ---------------- K5: in-place row L2 normalize ----------------
__global__ __launch_bounds__(256) void k5_norm(float* __restrict__ y) {
  __shared__ float red[4];
  int row = blockIdx.x;
  float* p = y + (size_t)row * 1024;
  int tid = threadIdx.x;
  float4 v = *(const float4*)(p + tid * 4);
  float ss = v.x * v.x + v.y * v.y + v.z * v.z + v.w * v.w;
#pragma unroll
  for (int m = 1; m < 64; m <<= 1) ss += __shfl_xor(ss, m, 64);
  if ((tid & 63) == 0) red[tid >> 6] = ss;
  __syncthreads();
  float tot = red[0] + red[1] + red[2] + red[3];
  float inv = 1.f / (sqrtf(tot) + 1e-8f);
  float4 o;
  o.x = v.x * inv; o.y = v.y * inv; o.z = v.z * inv; o.w = v.w * inv;
  *(float4*)(p + tid * 4) = o;
}

extern "C" void kernel_launch(void* const* d_in, const int* in_sizes, int n_in,
                              void* d_out, int out_size, void* d_ws, size_t ws_size,
                              hipStream_t stream) {
  const int* captions = (const int*)d_in[0];
  const float* H = (const float*)d_in[1];
  const int* targets = (const int*)d_in[2];
  const float* mask = (const float*)d_in[3];
  const float* Wa = (const float*)d_in[4];
  const float* Wc = (const float*)d_in[5];
  const float* fcw = (const float*)d_in[6];
  const float* fcb = (const float*)d_in[7];
  float* out = (float*)d_out;

  char* ws = (char*)d_ws;
  bf16* EA = (bf16*)(ws);                        // 16 MB [32][256][1024]
  bf16* ECT = (bf16*)(ws + (16u << 20));         // 16 MB [32][1024][256]
  bf16* X = (bf16*)(ws + (36u << 20));           // 32 MB [8192][2048]
  bf16* FW = (bf16*)(ws + (68u << 20));          //  4 MB [1024][2048]

  k1_prep<<<19456, 256, 0, stream>>>(captions, Wa, H, fcw, targets, Wc,
                                     EA, X, FW, ECT);
  k23_scores_pv<<<256, 256, 0, stream>>>(X, EA, ECT, mask);
  k4_fc<<<512, 256, 0, stream>>>(X, FW, fcb, out);
  k5_norm<<<8192, 256, 0, stream>>>(out);
}